// Round 7
// baseline (204.188 us; speedup 1.0000x reference)
//
#include <hip/hip_runtime.h>
#include <hip/hip_bf16.h>
#include <cstdint>

// Problem constants: B=2, T=2048, D_IN=D_OUT=1024, H=16, DH=64
#define SEQ_T 2048
#define DMODEL 1024
#define NHEAD 16
#define DHEAD 64

typedef __attribute__((ext_vector_type(8))) __bf16 bf16x8;
typedef __attribute__((ext_vector_type(4))) float floatx4;
typedef __attribute__((ext_vector_type(16))) float floatx16;
typedef __attribute__((ext_vector_type(2))) unsigned uint32x2;

static __device__ __forceinline__ uint16_t f2bf(float f) {
    union { float f; uint32_t u; } v; v.f = f;
    uint32_t r = v.u + 0x7FFFu + ((v.u >> 16) & 1u);   // RNE
    return (uint16_t)(r >> 16);
}

static __device__ __forceinline__ uint32_t pack2bf(float a, float b) {
    // compiler fuses paired casts into v_cvt_pk_bf16_f32 (m240: faster than hand asm)
    union { __bf16 h[2]; uint32_t u; } p;
    p.h[0] = (__bf16)a; p.h[1] = (__bf16)b;
    return p.u;
}

// -------- merged fp32->bf16 converts: z<4 weight transpose, z==4 x --------
// W_q (z==0) pre-scaled by 0.125*log2(e): QK^T emits s*C directly, so the
// attention softmax is a single raw v_exp_f32 (__builtin_amdgcn_exp2f).
__global__ void mha_cvt(const float* __restrict__ x, uint16_t* __restrict__ xb,
                        const float* __restrict__ W0, const float* __restrict__ W1,
                        const float* __restrict__ W2, const float* __restrict__ W3,
                        uint16_t* __restrict__ T0, uint16_t* __restrict__ T1,
                        uint16_t* __restrict__ T2, uint16_t* __restrict__ T3) {
    if (blockIdx.z == 4) {
        int base = (blockIdx.y * 16 + blockIdx.x) * 256 + threadIdx.x;
#pragma unroll
        for (int i = 0; i < 16; ++i) {
            int idx = base + i * 65536;
            float4 f = ((const float4*)x)[idx];
            union { uint16_t u[4]; uint64_t v; } o;
            o.u[0] = f2bf(f.x); o.u[1] = f2bf(f.y); o.u[2] = f2bf(f.z); o.u[3] = f2bf(f.w);
            ((uint64_t*)xb)[idx] = o.v;
        }
        return;
    }
    const float* W; uint16_t* Tt; float sc;
    switch (blockIdx.z) {
        case 0: W = W0; Tt = T0; sc = 0.125f * 1.44269504089f; break;
        case 1: W = W1; Tt = T1; sc = 1.f; break;
        case 2: W = W2; Tt = T2; sc = 1.f; break;
        default: W = W3; Tt = T3; sc = 1.f; break;
    }
    __shared__ float tile[64][65];
    const int c  = threadIdx.x & 63;
    const int r0 = threadIdx.x >> 6;
    const int R0 = blockIdx.y * 64, C0 = blockIdx.x * 64;
#pragma unroll
    for (int rr = 0; rr < 16; ++rr) {
        int r = r0 + rr * 4;
        tile[r][c] = W[(size_t)(R0 + r) * DMODEL + C0 + c];
    }
    __syncthreads();
#pragma unroll
    for (int rr = 0; rr < 16; ++rr) {
        int r = r0 + rr * 4;
        Tt[(size_t)(C0 + r) * DMODEL + R0 + c] = f2bf(tile[c][r] * sc);
    }
}

// ------ bf16 MFMA GEMM, 64M x 128N tile, BK=64, B^T input, swizzled ------
// (R10/R12-proven shape; qkv grid 1536 = 6 blocks/CU @ 24 KB dynamic LDS.
// R5's 128x128 retile was neutral-to-negative -> reverted to this config.)
// Swizzle: row r slot q' holds source sub-chunk q'^(r&7) -> 2-way-only.
// MODE 0: bf16 row-major out. MODE 1: Vt[(b*1024+col)*2048+t] via LDS
// transpose reusing staging smem.
template<int MODE>
__device__ __forceinline__ void gemm_bk64_body(
    const uint16_t* __restrict__ A, const uint16_t* __restrict__ Bt,
    uint16_t* __restrict__ outB) {
    const int K = DMODEL, N = DMODEL;
    extern __shared__ char smem[];                  // 24576 B dynamic
    uint16_t* As = (uint16_t*)smem;                 // [64][64]  8 KB
    uint16_t* Bs = (uint16_t*)(smem + 8192);        // [128][64] 16 KB
    const int tid  = threadIdx.x;
    const int wave = tid >> 6;
    const int lane = tid & 63;
    const int m0 = blockIdx.y * 64;
    const int n0 = blockIdx.x * 128;
    const int lr   = lane & 15;
    const int quad = lane >> 4;

    floatx4 acc[4][2];
#pragma unroll
    for (int i = 0; i < 4; ++i)
#pragma unroll
        for (int j = 0; j < 2; ++j) acc[i][j] = (floatx4)0.0f;

    for (int k0 = 0; k0 < K; k0 += 64) {
#pragma unroll
        for (int i = 0; i < 2; ++i) {               // A: 512 chunks (16B)
            int c = i * 256 + tid;
            int r = c >> 3, s = (c & 7) ^ (r & 7);
            const uint16_t* g = A + (size_t)(m0 + r) * K + k0 + s * 8;
            __builtin_amdgcn_global_load_lds((const __attribute__((address_space(1))) void*)g,
                                             (__attribute__((address_space(3))) void*)(As + (size_t)c * 8), 16, 0, 0);
        }
#pragma unroll
        for (int i = 0; i < 4; ++i) {               // B: 1024 chunks
            int c = i * 256 + tid;
            int r = c >> 3, s = (c & 7) ^ (r & 7);
            const uint16_t* g = Bt + (size_t)(n0 + r) * K + k0 + s * 8;
            __builtin_amdgcn_global_load_lds((const __attribute__((address_space(1))) void*)g,
                                             (__attribute__((address_space(3))) void*)(Bs + (size_t)c * 8), 16, 0, 0);
        }
        __syncthreads();
#pragma unroll
        for (int ks = 0; ks < 2; ++ks) {            // two 32-wide k-halves
            bf16x8 af[4], bfr[2];
#pragma unroll
            for (int mi = 0; mi < 4; ++mi) {
                int row = mi * 16 + lr;
                af[mi] = *(const bf16x8*)&As[row * 64 + (((ks * 4 + quad) ^ (row & 7)) << 3)];
            }
#pragma unroll
            for (int ni = 0; ni < 2; ++ni) {
                int row = wave * 32 + ni * 16 + lr;
                bfr[ni] = *(const bf16x8*)&Bs[row * 64 + (((ks * 4 + quad) ^ (row & 7)) << 3)];
            }
#pragma unroll
            for (int mi = 0; mi < 4; ++mi)
#pragma unroll
                for (int ni = 0; ni < 2; ++ni)
                    acc[mi][ni] = __builtin_amdgcn_mfma_f32_16x16x32_bf16(af[mi], bfr[ni], acc[mi][ni], 0, 0, 0);
        }
        __syncthreads();
    }
    if constexpr (MODE == 1) {
        uint16_t* Ct = (uint16_t*)smem;             // [128][72], 18.4 KB
        const int bb = m0 >> 11, t0 = m0 & 2047;
#pragma unroll
        for (int mi = 0; mi < 4; ++mi)
#pragma unroll
            for (int ni = 0; ni < 2; ++ni) {
                int cl = wave * 32 + ni * 16 + lr;
                int tl = mi * 16 + quad * 4;
                int tls = tl ^ ((cl & 3) << 4);     // 2-way-only bank pattern
                union { uint16_t u[4]; uint64_t v8; } pk;
#pragma unroll
                for (int r = 0; r < 4; ++r) pk.u[r] = f2bf(acc[mi][ni][r]);
                *(uint64_t*)&Ct[cl * 72 + tls] = pk.v8;
            }
        __syncthreads();
#pragma unroll
        for (int k = 0; k < 4; ++k) {
            int c = k * 256 + tid;                  // 1024 chunks of 16B
            int cl = c >> 3, off = (c & 7) * 8;
            int offs = off ^ ((cl & 3) << 4);
            uint4 v = *(const uint4*)&Ct[cl * 72 + offs];
            *(uint4*)&outB[((size_t)(bb * 1024 + n0 + cl)) * 2048 + t0 + off] = v;
        }
    } else {
#pragma unroll
        for (int mi = 0; mi < 4; ++mi)
#pragma unroll
            for (int ni = 0; ni < 2; ++ni) {
                int col = n0 + wave * 32 + ni * 16 + lr;
#pragma unroll
                for (int r = 0; r < 4; ++r) {
                    int row = m0 + mi * 16 + quad * 4 + r;
                    outB[(size_t)row * N + col] = f2bf(acc[mi][ni][r]);
                }
            }
    }
}

__global__ __launch_bounds__(256) void mha_gemm_qkv(
    const uint16_t* __restrict__ A,
    const uint16_t* __restrict__ Wq, const uint16_t* __restrict__ Wk, const uint16_t* __restrict__ Wv,
    uint16_t* __restrict__ Q, uint16_t* __restrict__ K, uint16_t* __restrict__ Vt) {
    switch (blockIdx.z) {
        case 0:  gemm_bk64_body<0>(A, Wq, Q);  break;
        case 1:  gemm_bk64_body<0>(A, Wk, K);  break;
        default: gemm_bk64_body<1>(A, Wv, Vt); break;
    }
}

// ---- out-projection GEMM: 64M x 128N, BK=64, 512 thr / 8 waves ----
// (R14-best config: wave-tile 32x32, grid (8,64) = 2 blocks/CU x 8 waves
// = 16 waves/CU. R15's 64x64 retile regressed ~3.6 µs — reverted.)
__global__ __launch_bounds__(512) void mha_gemm_out(
    const uint16_t* __restrict__ A, const uint16_t* __restrict__ Wot,
    float* __restrict__ out, const float* __restrict__ bias) {
    const int K = DMODEL, N = DMODEL;
    extern __shared__ char smem[];                  // 24576 B dynamic
    uint16_t* As = (uint16_t*)smem;                 // [64][64]  8 KB
    uint16_t* Bs = (uint16_t*)(smem + 8192);        // [128][64] 16 KB
    const int tid  = threadIdx.x;
    const int wave = tid >> 6;
    const int lane = tid & 63;
    const int m0 = blockIdx.y * 64;
    const int n0 = blockIdx.x * 128;
    const int lr   = lane & 15;
    const int quad = lane >> 4;
    const int wm = wave >> 2, wn = wave & 3;        // 2m x 4n wave grid

    floatx4 acc[2][2];
#pragma unroll
    for (int i = 0; i < 2; ++i)
#pragma unroll
        for (int j = 0; j < 2; ++j) acc[i][j] = (floatx4)0.0f;

    for (int k0 = 0; k0 < K; k0 += 64) {
        {                                           // A: 512 chunks
            int c = tid;
            int r = c >> 3, s = (c & 7) ^ (r & 7);
            const uint16_t* g = A + (size_t)(m0 + r) * K + k0 + s * 8;
            __builtin_amdgcn_global_load_lds((const __attribute__((address_space(1))) void*)g,
                                             (__attribute__((address_space(3))) void*)(As + (size_t)c * 8), 16, 0, 0);
        }
#pragma unroll
        for (int i = 0; i < 2; ++i) {               // B: 1024 chunks
            int c = i * 512 + tid;
            int r = c >> 3, s = (c & 7) ^ (r & 7);
            const uint16_t* g = Wot + (size_t)(n0 + r) * K + k0 + s * 8;
            __builtin_amdgcn_global_load_lds((const __attribute__((address_space(1))) void*)g,
                                             (__attribute__((address_space(3))) void*)(Bs + (size_t)c * 8), 16, 0, 0);
        }
        __syncthreads();
#pragma unroll
        for (int ks = 0; ks < 2; ++ks) {
            bf16x8 af[2], bfr[2];
#pragma unroll
            for (int mi = 0; mi < 2; ++mi) {
                int row = wm * 32 + mi * 16 + lr;
                af[mi] = *(const bf16x8*)&As[row * 64 + (((ks * 4 + quad) ^ (row & 7)) << 3)];
            }
#pragma unroll
            for (int ni = 0; ni < 2; ++ni) {
                int row = wn * 32 + ni * 16 + lr;
                bfr[ni] = *(const bf16x8*)&Bs[row * 64 + (((ks * 4 + quad) ^ (row & 7)) << 3)];
            }
#pragma unroll
            for (int mi = 0; mi < 2; ++mi)
#pragma unroll
                for (int ni = 0; ni < 2; ++ni)
                    acc[mi][ni] = __builtin_amdgcn_mfma_f32_16x16x32_bf16(af[mi], bfr[ni], acc[mi][ni], 0, 0, 0);
        }
        __syncthreads();
    }
#pragma unroll
    for (int mi = 0; mi < 2; ++mi)
#pragma unroll
        for (int ni = 0; ni < 2; ++ni) {
            int col = n0 + wn * 32 + ni * 16 + lr;
            float bv = bias[col];
#pragma unroll
            for (int r = 0; r < 4; ++r) {
                int row = m0 + wm * 32 + mi * 16 + quad * 4 + r;
                out[(size_t)row * N + col] = acc[mi][ni][r] + bv;
            }
        }
}

// ---------------- MFMA flash attention (causal, fixed-base softmax) -------
// R7: staging-DMA attack. Cross-round invariant: every variant stages
// ~544 KB K+V per block via global_load_lds and wall time == staged
// bytes / ~10 B/cyc/CU (R0/R1/R2/R6 at 2 blocks/CU: 1.09MB -> 105-117k
// cyc; R3 at 1 block/CU: 576KB -> 100k cyc = 5.9 B/cyc). The kernel is
// DMA-throughput-bound, not occupancy/LDS/barrier-bound. Fix: halve DMA
// bytes — stage only K; read V fragments DIRECT from global Vt (plain
// [d][t] layout, 16B contiguous per lane; per-XCD L2-resident via h%8;
// vector-load path is distinct from the LDS-DMA path; m169 precedent).
//   * geometry unchanged from R6: q 64-row pairs (31-p, p), kv supertile
//     128, 17 iters, grid (16,16,2) x 512 thr, 8 waves = 2qg x 4kvq.
//   * LDS 33 KB: Ks[2][128x64] 32K + lbuf 1K. Merge o-scratch reuses
//     dead Ks[cur] (16 KB f32).
//   * __launch_bounds__(512,2): R6's (512,4) forced VGPR 64 + scratch
//     spills (WRITE_SIZE 8->36 MB) — the regression cause. R3 measured
//     120 VGPR spill-free at (512,2); <=128 still allows 4 waves/SIMD.
//   * registers slimmed: se[16] folded into the exp2->pack loop.
__global__ __launch_bounds__(512, 2) void mha_attn_mfma(
    const uint16_t* __restrict__ Q, const uint16_t* __restrict__ K,
    const uint16_t* __restrict__ Vt, uint16_t* __restrict__ ctx) {
    __shared__ alignas(16) uint16_t Ks[2][128 * 64];   // 32 KB [kv][d]
    __shared__ float lbuf[256];                        // 1 KB l/linv scratch

    const int tid  = threadIdx.x;
    const int wave = tid >> 6;
    const int lane = tid & 63;
    const int l31  = lane & 31;
    const int hi   = lane >> 5;
    const int l7   = lane & 7;
    const int qg   = wave & 1;             // q-row group (32 rows)
    const int kvq  = wave >> 1;            // kv quarter: 32 kv cols each
    const int h = blockIdx.x;              // head fastest -> XCD locality
    const int p = blockIdx.y;              // 0..15
    const int b = blockIdx.z;
    const int jH = 31 - p, jL = p;         // paired 64-row q-tiles
    const int TH = (33 - p) >> 1;          // 128-wide supertiles; TH+TL=17

    // K staging: 2 chunks/thread, XOR source swizzle, linear LDS dest
    const uint16_t* kg[2];
    int cch[2];
#pragma unroll
    for (int i = 0; i < 2; ++i) {
        int c = i * 512 + tid; cch[i] = c;        // chunk 0..1023 (16 B)
        int rk = c >> 3, ck = c & 7;              // K: 128 rows x 8 chunks
        kg[i] = K + ((size_t)(b * SEQ_T) + rk) * DMODEL + h * DHEAD + ((ck ^ (rk & 7)) * 8);
    }
    // V read direct: plain [d][t], row = dt*32+l31, 16B chunks along kv
    const uint16_t* Vg = Vt + ((size_t)(b * 1024 + h * DHEAD)) * 2048;

    int q0w = jH * 64 + qg * 32;           // this wave's q base
    bf16x8 qf[4];
    auto load_q = [&]() {
        const uint16_t* qb = Q + ((size_t)(b * SEQ_T) + q0w + l31) * DMODEL + h * DHEAD;
#pragma unroll
        for (int f = 0; f < 4; ++f)
            qf[f] = *(const bf16x8*)(qb + f * 16 + hi * 8);
    };
    load_q();

    floatx16 o[2];
#pragma unroll
    for (int dt = 0; dt < 2; ++dt) o[dt] = (floatx16)0.0f;
    float lac = 0.f;

    auto stage = [&](int kv0, int buf) {   // 2 global_load_lds per thread
#pragma unroll
        for (int i = 0; i < 2; ++i)
            __builtin_amdgcn_global_load_lds(
                (const __attribute__((address_space(1))) void*)(kg[i] + (size_t)kv0 * DMODEL),
                (__attribute__((address_space(3))) void*)(&Ks[buf][cch[i] * 8]), 16, 0, 0);
    };

    // own + partner-half value (lane l <-> l^32) summed
    auto halfsum = [&](float x) -> float {
#if __has_builtin(__builtin_amdgcn_permlane32_swap)
        uint32x2 r = __builtin_amdgcn_permlane32_swap(__float_as_uint(x), __float_as_uint(x), false, false);
        return __uint_as_float(r.x) + __uint_as_float(r.y);
#else
        return x + __shfl_xor(x, 32, 64);
#endif
    };

    // merge kvq 3->2->1 partials into kvq 0 (fixed-base softmax => o,l
    // additive). o-scratch = dead Ks[cur] ([64 q][64 d] f32 = 16 KB);
    // l scratch = lbuf. All reads of Ks[cur] finished at the entry
    // barrier; in-flight DMA targets cur^1; the next DMA into cur is
    // issued only after the loop-bottom barrier.
    auto combine_store = [&](int cur) {
        __syncthreads();
        float* osc = (float*)&Ks[cur][0];         // [64 q][64 d] f32
        float lt = halfsum(lac);
#pragma unroll
        for (int pass = 3; pass >= 1; --pass) {
            if (kvq == pass) {
                if (pass == 3) {
#pragma unroll
                    for (int dt = 0; dt < 2; ++dt)
#pragma unroll
                        for (int r = 0; r < 16; ++r) {
                            int row = (r & 3) + 8 * (r >> 2) + 4 * hi;
                            osc[(qg * 32 + row) * 64 + dt * 32 + l31] = o[dt][r];
                        }
                    if (lane < 32) lbuf[qg * 32 + lane] = lt;
                } else {
#pragma unroll
                    for (int dt = 0; dt < 2; ++dt)
#pragma unroll
                        for (int r = 0; r < 16; ++r) {
                            int row = (r & 3) + 8 * (r >> 2) + 4 * hi;
                            osc[(qg * 32 + row) * 64 + dt * 32 + l31] += o[dt][r];
                        }
                    if (lane < 32) lbuf[qg * 32 + lane] += lt;
                }
            }
            __syncthreads();
        }
        if (kvq == 0) {
            float ltot = lt + lbuf[qg * 32 + l31];
            if (lane < 32) lbuf[64 + qg * 32 + lane] = 1.f / ltot;
#pragma unroll
            for (int dt = 0; dt < 2; ++dt)
#pragma unroll
                for (int r = 0; r < 16; ++r) {
                    int row = (r & 3) + 8 * (r >> 2) + 4 * hi;
                    float ov = o[dt][r] + osc[(qg * 32 + row) * 64 + dt * 32 + l31];
                    float li = lbuf[64 + qg * 32 + row];    // broadcast read
                    size_t addr = ((size_t)(b * SEQ_T) + q0w + row) * DMODEL + h * DHEAD + dt * 32 + l31;
                    ctx[addr] = f2bf(ov * li);
                }
        }
    };

    stage(0, 0);
    __syncthreads();

    for (int t = 0; t < 17; ++t) {
        const int cur = t & 1;
        const int kv0 = (t < TH ? t : t - TH) * 128;
        if (t + 1 < 17) {
            int tn = t + 1;
            stage((tn < TH ? tn : tn - TH) * 128, tn & 1);
        }
        const int kb = kv0 + kvq * 32;
        // QK^T swapped: S^T[k][q] = mfma(K, Q); lane: q = l31, k by reg
        floatx16 s = (floatx16)0.0f;
        __builtin_amdgcn_s_setprio(1);
#pragma unroll
        for (int f = 0; f < 4; ++f) {
            bf16x8 kf = *(const bf16x8*)&Ks[cur][(kvq * 32 + l31) * 64 + (((2 * f + hi) ^ l7) << 3)];
            s = __builtin_amdgcn_mfma_f32_32x32x16_bf16(kf, qf[f], s, 0, 0, 0);
        }
        __builtin_amdgcn_s_setprio(0);
        if (kb + 31 > q0w) {               // causal mask (covers overhang)
            int qr = q0w + l31;
#pragma unroll
            for (int r = 0; r < 16; ++r) {
                int k = kb + (r & 3) + 8 * (r >> 2) + 4 * hi;
                if (k > qr) s[r] = -3e38f;
            }
        }
        // p = exp2(s) (scale folded into W_q); l rides a VALU sum.
        // exp2+pack fused (no se[16] array -> shorter live ranges).
        uint32_t d0[2], d1[2], d2[2], d3[2];
#pragma unroll
        for (int i = 0; i < 2; ++i) {
            float a, c2;
            a = __builtin_amdgcn_exp2f(s[2 * i]);      c2 = __builtin_amdgcn_exp2f(s[2 * i + 1]);
            lac += a + c2; d0[i] = pack2bf(a, c2);
            a = __builtin_amdgcn_exp2f(s[4 + 2 * i]);  c2 = __builtin_amdgcn_exp2f(s[4 + 2 * i + 1]);
            lac += a + c2; d1[i] = pack2bf(a, c2);
            a = __builtin_amdgcn_exp2f(s[8 + 2 * i]);  c2 = __builtin_amdgcn_exp2f(s[8 + 2 * i + 1]);
            lac += a + c2; d2[i] = pack2bf(a, c2);
            a = __builtin_amdgcn_exp2f(s[12 + 2 * i]); c2 = __builtin_amdgcn_exp2f(s[12 + 2 * i + 1]);
            lac += a + c2; d3[i] = pack2bf(a, c2);
        }
        // redistribute across lane halves -> PV A-frags (k contiguous)
        bf16x8 paf[2];
#if __has_builtin(__builtin_amdgcn_permlane32_swap)
        {
            uint32x2 r0 = __builtin_amdgcn_permlane32_swap(d0[0], d1[0], false, false);
            uint32x2 r1 = __builtin_amdgcn_permlane32_swap(d0[1], d1[1], false, false);
            union { uint32_t u[4]; bf16x8 v; } f0;
            f0.u[0] = r0.x; f0.u[1] = r1.x; f0.u[2] = r0.y; f0.u[3] = r1.y;
            paf[0] = f0.v;
            uint32x2 r2 = __builtin_amdgcn_permlane32_swap(d2[0], d3[0], false, false);
            uint32x2 r3 = __builtin_amdgcn_permlane32_swap(d2[1], d3[1], false, false);
            union { uint32_t u[4]; bf16x8 v; } f1;
            f1.u[0] = r2.x; f1.u[1] = r3.x; f1.u[2] = r2.y; f1.u[3] = r3.y;
            paf[1] = f1.v;
        }
#else
        {
            uint32_t s00 = __shfl_xor((int)d0[0], 32, 64), s01 = __shfl_xor((int)d0[1], 32, 64);
            uint32_t s10 = __shfl_xor((int)d1[0], 32, 64), s11 = __shfl_xor((int)d1[1], 32, 64);
            union { uint32_t u[4]; bf16x8 v; } f0;
            f0.u[0] = hi ? s10 : d0[0]; f0.u[1] = hi ? s11 : d0[1];
            f0.u[2] = hi ? d1[0] : s00; f0.u[3] = hi ? d1[1] : s01;
            paf[0] = f0.v;
            uint32_t s20 = __shfl_xor((int)d2[0], 32, 64), s21 = __shfl_xor((int)d2[1], 32, 64);
            uint32_t s30 = __shfl_xor((int)d3[0], 32, 64), s31 = __shfl_xor((int)d3[1], 32, 64);
            union { uint32_t u[4]; bf16x8 v; } f1;
            f1.u[0] = hi ? s30 : d2[0]; f1.u[1] = hi ? s31 : d2[1];
            f1.u[2] = hi ? d3[0] : s20; f1.u[3] = hi ? d3[1] : s21;
            paf[1] = f1.v;
        }
#endif
        // PV: O[q][d] += P x V  (A = in-reg P, B = V^T rows DIRECT from
        // global Vt — L2-resident per XCD, no LDS staging for V)
        __builtin_amdgcn_s_setprio(1);
#pragma unroll
        for (int f = 0; f < 2; ++f)
#pragma unroll
            for (int dt = 0; dt < 2; ++dt) {
                bf16x8 vf = *(const bf16x8*)&Vg[(size_t)(dt * 32 + l31) * 2048 + kv0 + ((kvq * 4 + 2 * f + hi) * 8)];
                o[dt] = __builtin_amdgcn_mfma_f32_32x32x16_bf16(paf[f], vf, o[dt], 0, 0, 0);
            }
        __builtin_amdgcn_s_setprio(0);
        if (t == TH - 1) {                 // high q-tile done: merge + store
            combine_store(cur);
            q0w = jL * 64 + qg * 32;
            load_q();
#pragma unroll
            for (int dt = 0; dt < 2; ++dt) o[dt] = (floatx16)0.0f;
            lac = 0.f;
        }
        if (t + 1 < 17) __syncthreads();   // next K buffer staged & landed
    }
    combine_store(0);                      // t=16 -> cur=0
}

extern "C" void kernel_launch(void* const* d_in, const int* in_sizes, int n_in,
                              void* d_out, int out_size, void* d_ws, size_t ws_size,
                              hipStream_t stream) {
    const float* x  = (const float*)d_in[0];
    const float* Wq = (const float*)d_in[1];
    const float* Wk = (const float*)d_in[2];
    const float* Wv = (const float*)d_in[3];
    const float* Wo = (const float*)d_in[4];
    const float* bo = (const float*)d_in[5];
    float* out = (float*)d_out;

    char* ws = (char*)d_ws;
    const size_t SZ_X = (size_t)4096 * DMODEL * 2;   // 8 MB
    const size_t SZ_W = (size_t)DMODEL * DMODEL * 2; // 2 MB
    size_t off = 0;
    uint16_t* xb  = (uint16_t*)(ws + off); off += SZ_X;
    uint16_t* wqt = (uint16_t*)(ws + off); off += SZ_W;
    uint16_t* wkt = (uint16_t*)(ws + off); off += SZ_W;
    uint16_t* wvt = (uint16_t*)(ws + off); off += SZ_W;
    uint16_t* wot = (uint16_t*)(ws + off); off += SZ_W;
    uint16_t* Qb  = (uint16_t*)(ws + off); off += SZ_X;
    uint16_t* Kb  = (uint16_t*)(ws + off); off += SZ_X;
    uint16_t* Vtb = (uint16_t*)(ws + off); off += SZ_X;  // per-head transposed V
    uint16_t* Cb  = (uint16_t*)(ws + off); off += SZ_X;
    (void)ws_size; (void)in_sizes; (void)n_in; (void)out_size;

    mha_cvt<<<dim3(16, 16, 5), 256, 0, stream>>>(x, xb, Wq, Wk, Wv, Wo, wqt, wkt, wvt, wot);
    mha_gemm_qkv<<<dim3(8, 64, 3), 256, 24576, stream>>>(xb, wqt, wkt, wvt, Qb, Kb, Vtb);
    mha_attn_mfma<<<dim3(NHEAD, 16, 2), 512, 0, stream>>>(Qb, Kb, Vtb, Cb);
    mha_gemm_out<<<dim3(8, 64), 512, 24576, stream>>>(Cb, wot, out, bo);
}

// Round 8
// 180.996 us; speedup vs baseline: 1.1281x; 1.1281x over previous
//
#include <hip/hip_runtime.h>
#include <hip/hip_bf16.h>
#include <cstdint>

// Problem constants: B=2, T=2048, D_IN=D_OUT=1024, H=16, DH=64
#define SEQ_T 2048
#define DMODEL 1024
#define NHEAD 16
#define DHEAD 64

typedef __attribute__((ext_vector_type(8))) __bf16 bf16x8;
typedef __attribute__((ext_vector_type(4))) float floatx4;
typedef __attribute__((ext_vector_type(16))) float floatx16;
typedef __attribute__((ext_vector_type(2))) unsigned uint32x2;

static __device__ __forceinline__ uint16_t f2bf(float f) {
    union { float f; uint32_t u; } v; v.f = f;
    uint32_t r = v.u + 0x7FFFu + ((v.u >> 16) & 1u);   // RNE
    return (uint16_t)(r >> 16);
}

static __device__ __forceinline__ uint32_t pack2bf(float a, float b) {
    // compiler fuses paired casts into v_cvt_pk_bf16_f32 (m240: faster than hand asm)
    union { __bf16 h[2]; uint32_t u; } p;
    p.h[0] = (__bf16)a; p.h[1] = (__bf16)b;
    return p.u;
}

// -------- merged fp32->bf16 converts: z<4 weight transpose, z==4 x --------
// W_q (z==0) pre-scaled by 0.125*log2(e): QK^T emits s*C directly, so the
// attention softmax is a single raw v_exp_f32 (__builtin_amdgcn_exp2f).
__global__ void mha_cvt(const float* __restrict__ x, uint16_t* __restrict__ xb,
                        const float* __restrict__ W0, const float* __restrict__ W1,
                        const float* __restrict__ W2, const float* __restrict__ W3,
                        uint16_t* __restrict__ T0, uint16_t* __restrict__ T1,
                        uint16_t* __restrict__ T2, uint16_t* __restrict__ T3) {
    if (blockIdx.z == 4) {
        int base = (blockIdx.y * 16 + blockIdx.x) * 256 + threadIdx.x;
#pragma unroll
        for (int i = 0; i < 16; ++i) {
            int idx = base + i * 65536;
            float4 f = ((const float4*)x)[idx];
            union { uint16_t u[4]; uint64_t v; } o;
            o.u[0] = f2bf(f.x); o.u[1] = f2bf(f.y); o.u[2] = f2bf(f.z); o.u[3] = f2bf(f.w);
            ((uint64_t*)xb)[idx] = o.v;
        }
        return;
    }
    const float* W; uint16_t* Tt; float sc;
    switch (blockIdx.z) {
        case 0: W = W0; Tt = T0; sc = 0.125f * 1.44269504089f; break;
        case 1: W = W1; Tt = T1; sc = 1.f; break;
        case 2: W = W2; Tt = T2; sc = 1.f; break;
        default: W = W3; Tt = T3; sc = 1.f; break;
    }
    __shared__ float tile[64][65];
    const int c  = threadIdx.x & 63;
    const int r0 = threadIdx.x >> 6;
    const int R0 = blockIdx.y * 64, C0 = blockIdx.x * 64;
#pragma unroll
    for (int rr = 0; rr < 16; ++rr) {
        int r = r0 + rr * 4;
        tile[r][c] = W[(size_t)(R0 + r) * DMODEL + C0 + c];
    }
    __syncthreads();
#pragma unroll
    for (int rr = 0; rr < 16; ++rr) {
        int r = r0 + rr * 4;
        Tt[(size_t)(C0 + r) * DMODEL + R0 + c] = f2bf(tile[c][r] * sc);
    }
}

// ------ bf16 MFMA GEMM, 64M x 128N tile, BK=64, B^T input, swizzled ------
// (R10/R12-proven shape; qkv grid 1536 = 6 blocks/CU @ 24 KB dynamic LDS.
// R5's 128x128 retile was neutral-to-negative -> reverted to this config.)
// Swizzle: row r slot q' holds source sub-chunk q'^(r&7) -> 2-way-only.
// MODE 0: bf16 row-major out. MODE 1: Vt[(b*1024+col)*2048+t] via LDS
// transpose reusing staging smem.
template<int MODE>
__device__ __forceinline__ void gemm_bk64_body(
    const uint16_t* __restrict__ A, const uint16_t* __restrict__ Bt,
    uint16_t* __restrict__ outB) {
    const int K = DMODEL, N = DMODEL;
    extern __shared__ char smem[];                  // 24576 B dynamic
    uint16_t* As = (uint16_t*)smem;                 // [64][64]  8 KB
    uint16_t* Bs = (uint16_t*)(smem + 8192);        // [128][64] 16 KB
    const int tid  = threadIdx.x;
    const int wave = tid >> 6;
    const int lane = tid & 63;
    const int m0 = blockIdx.y * 64;
    const int n0 = blockIdx.x * 128;
    const int lr   = lane & 15;
    const int quad = lane >> 4;

    floatx4 acc[4][2];
#pragma unroll
    for (int i = 0; i < 4; ++i)
#pragma unroll
        for (int j = 0; j < 2; ++j) acc[i][j] = (floatx4)0.0f;

    for (int k0 = 0; k0 < K; k0 += 64) {
#pragma unroll
        for (int i = 0; i < 2; ++i) {               // A: 512 chunks (16B)
            int c = i * 256 + tid;
            int r = c >> 3, s = (c & 7) ^ (r & 7);
            const uint16_t* g = A + (size_t)(m0 + r) * K + k0 + s * 8;
            __builtin_amdgcn_global_load_lds((const __attribute__((address_space(1))) void*)g,
                                             (__attribute__((address_space(3))) void*)(As + (size_t)c * 8), 16, 0, 0);
        }
#pragma unroll
        for (int i = 0; i < 4; ++i) {               // B: 1024 chunks
            int c = i * 256 + tid;
            int r = c >> 3, s = (c & 7) ^ (r & 7);
            const uint16_t* g = Bt + (size_t)(n0 + r) * K + k0 + s * 8;
            __builtin_amdgcn_global_load_lds((const __attribute__((address_space(1))) void*)g,
                                             (__attribute__((address_space(3))) void*)(Bs + (size_t)c * 8), 16, 0, 0);
        }
        __syncthreads();
#pragma unroll
        for (int ks = 0; ks < 2; ++ks) {            // two 32-wide k-halves
            bf16x8 af[4], bfr[2];
#pragma unroll
            for (int mi = 0; mi < 4; ++mi) {
                int row = mi * 16 + lr;
                af[mi] = *(const bf16x8*)&As[row * 64 + (((ks * 4 + quad) ^ (row & 7)) << 3)];
            }
#pragma unroll
            for (int ni = 0; ni < 2; ++ni) {
                int row = wave * 32 + ni * 16 + lr;
                bfr[ni] = *(const bf16x8*)&Bs[row * 64 + (((ks * 4 + quad) ^ (row & 7)) << 3)];
            }
#pragma unroll
            for (int mi = 0; mi < 4; ++mi)
#pragma unroll
                for (int ni = 0; ni < 2; ++ni)
                    acc[mi][ni] = __builtin_amdgcn_mfma_f32_16x16x32_bf16(af[mi], bfr[ni], acc[mi][ni], 0, 0, 0);
        }
        __syncthreads();
    }
    if constexpr (MODE == 1) {
        uint16_t* Ct = (uint16_t*)smem;             // [128][72], 18.4 KB
        const int bb = m0 >> 11, t0 = m0 & 2047;
#pragma unroll
        for (int mi = 0; mi < 4; ++mi)
#pragma unroll
            for (int ni = 0; ni < 2; ++ni) {
                int cl = wave * 32 + ni * 16 + lr;
                int tl = mi * 16 + quad * 4;
                int tls = tl ^ ((cl & 3) << 4);     // 2-way-only bank pattern
                union { uint16_t u[4]; uint64_t v8; } pk;
#pragma unroll
                for (int r = 0; r < 4; ++r) pk.u[r] = f2bf(acc[mi][ni][r]);
                *(uint64_t*)&Ct[cl * 72 + tls] = pk.v8;
            }
        __syncthreads();
#pragma unroll
        for (int k = 0; k < 4; ++k) {
            int c = k * 256 + tid;                  // 1024 chunks of 16B
            int cl = c >> 3, off = (c & 7) * 8;
            int offs = off ^ ((cl & 3) << 4);
            uint4 v = *(const uint4*)&Ct[cl * 72 + offs];
            *(uint4*)&outB[((size_t)(bb * 1024 + n0 + cl)) * 2048 + t0 + off] = v;
        }
    } else {
#pragma unroll
        for (int mi = 0; mi < 4; ++mi)
#pragma unroll
            for (int ni = 0; ni < 2; ++ni) {
                int col = n0 + wave * 32 + ni * 16 + lr;
#pragma unroll
                for (int r = 0; r < 4; ++r) {
                    int row = m0 + mi * 16 + quad * 4 + r;
                    outB[(size_t)row * N + col] = f2bf(acc[mi][ni][r]);
                }
            }
    }
}

__global__ __launch_bounds__(256) void mha_gemm_qkv(
    const uint16_t* __restrict__ A,
    const uint16_t* __restrict__ Wq, const uint16_t* __restrict__ Wk, const uint16_t* __restrict__ Wv,
    uint16_t* __restrict__ Q, uint16_t* __restrict__ K, uint16_t* __restrict__ Vt) {
    switch (blockIdx.z) {
        case 0:  gemm_bk64_body<0>(A, Wq, Q);  break;
        case 1:  gemm_bk64_body<0>(A, Wk, K);  break;
        default: gemm_bk64_body<1>(A, Wv, Vt); break;
    }
}

// ---- out-projection GEMM: 64M x 128N, BK=64, 512 thr / 8 waves ----
// (R14-best config: wave-tile 32x32, grid (8,64) = 2 blocks/CU x 8 waves
// = 16 waves/CU. R15's 64x64 retile regressed ~3.6 µs — reverted.)
__global__ __launch_bounds__(512) void mha_gemm_out(
    const uint16_t* __restrict__ A, const uint16_t* __restrict__ Wot,
    float* __restrict__ out, const float* __restrict__ bias) {
    const int K = DMODEL, N = DMODEL;
    extern __shared__ char smem[];                  // 24576 B dynamic
    uint16_t* As = (uint16_t*)smem;                 // [64][64]  8 KB
    uint16_t* Bs = (uint16_t*)(smem + 8192);        // [128][64] 16 KB
    const int tid  = threadIdx.x;
    const int wave = tid >> 6;
    const int lane = tid & 63;
    const int m0 = blockIdx.y * 64;
    const int n0 = blockIdx.x * 128;
    const int lr   = lane & 15;
    const int quad = lane >> 4;
    const int wm = wave >> 2, wn = wave & 3;        // 2m x 4n wave grid

    floatx4 acc[2][2];
#pragma unroll
    for (int i = 0; i < 2; ++i)
#pragma unroll
        for (int j = 0; j < 2; ++j) acc[i][j] = (floatx4)0.0f;

    for (int k0 = 0; k0 < K; k0 += 64) {
        {                                           // A: 512 chunks
            int c = tid;
            int r = c >> 3, s = (c & 7) ^ (r & 7);
            const uint16_t* g = A + (size_t)(m0 + r) * K + k0 + s * 8;
            __builtin_amdgcn_global_load_lds((const __attribute__((address_space(1))) void*)g,
                                             (__attribute__((address_space(3))) void*)(As + (size_t)c * 8), 16, 0, 0);
        }
#pragma unroll
        for (int i = 0; i < 2; ++i) {               // B: 1024 chunks
            int c = i * 512 + tid;
            int r = c >> 3, s = (c & 7) ^ (r & 7);
            const uint16_t* g = Wot + (size_t)(n0 + r) * K + k0 + s * 8;
            __builtin_amdgcn_global_load_lds((const __attribute__((address_space(1))) void*)g,
                                             (__attribute__((address_space(3))) void*)(Bs + (size_t)c * 8), 16, 0, 0);
        }
        __syncthreads();
#pragma unroll
        for (int ks = 0; ks < 2; ++ks) {
            bf16x8 af[2], bfr[2];
#pragma unroll
            for (int mi = 0; mi < 2; ++mi) {
                int row = wm * 32 + mi * 16 + lr;
                af[mi] = *(const bf16x8*)&As[row * 64 + (((ks * 4 + quad) ^ (row & 7)) << 3)];
            }
#pragma unroll
            for (int ni = 0; ni < 2; ++ni) {
                int row = wn * 32 + ni * 16 + lr;
                bfr[ni] = *(const bf16x8*)&Bs[row * 64 + (((ks * 4 + quad) ^ (row & 7)) << 3)];
            }
#pragma unroll
            for (int mi = 0; mi < 2; ++mi)
#pragma unroll
                for (int ni = 0; ni < 2; ++ni)
                    acc[mi][ni] = __builtin_amdgcn_mfma_f32_16x16x32_bf16(af[mi], bfr[ni], acc[mi][ni], 0, 0, 0);
        }
        __syncthreads();
    }
#pragma unroll
    for (int mi = 0; mi < 2; ++mi)
#pragma unroll
        for (int ni = 0; ni < 2; ++ni) {
            int col = n0 + wn * 32 + ni * 16 + lr;
            float bv = bias[col];
#pragma unroll
            for (int r = 0; r < 4; ++r) {
                int row = m0 + wm * 32 + mi * 16 + quad * 4 + r;
                out[(size_t)row * N + col] = acc[mi][ni][r] + bv;
            }
        }
}

// ---------------- MFMA flash attention (causal, fixed-base softmax) -------
// R8: combine the two measured DMA levers. Cross-round books: q-tile 64
// variants stage 278 MB total; q-tile 128 halves that to 139 MB (R3).
// Separately, 16 waves/CU doubles achieved DMA rate vs 8 (R1/R2: ~10
// B/cyc/CU vs R3: 5.9). Never combined until now:
//   * ONE 1024-thread block (16 waves) per CU: grid (16 h, 8 p, 2 b) =
//     256 = 1 block/CU. Waves = 4 qg(32 q-rows) x 4 kvq(32 kv).
//   * q-tile 128, pairs jH=15-p / jL=p; kv supertile 128; TH=jH+1,
//     TH+TL=17 iters. Staged = 544 KB/block = 544 KB/CU (half of R1's).
//   * LDS 65 KB dynamic: Ks[2][128x64] 32K + Vs[2][64x128] 32K + lbuf 1K.
//   * __launch_bounds__(1024) forces VGPR <= 128 (16 resident waves);
//     this per-wave structure measured 92 VGPR in R7 — no spill expected
//     (R6's spill came from the explicit min-waves=4 arg forcing 64).
//   * R7's direct-V is reverted: V lane->address mapping was uncoalesced
//     (lane indexes d => 4KB stride). Staged V restored (R6-verified).
// Per-wave code (staging swizzles, QK/PV fragment reads, in-reg softmax,
// 4-way kvq merge) is the R6-verified code re-parameterized; merge
// o-scratch spans both dead cur-buffers (Ks[cur]: qg<2, Vs[cur]: qg>=2).
__global__ __launch_bounds__(1024) void mha_attn_mfma(
    const uint16_t* __restrict__ Q, const uint16_t* __restrict__ K,
    const uint16_t* __restrict__ Vt, uint16_t* __restrict__ ctx) {
    extern __shared__ char asmem[];
    uint16_t* Ks0 = (uint16_t*)asmem;              // [2][128*64] 32 KB [kv][d]
    uint16_t* Vs0 = (uint16_t*)(asmem + 32768);    // [2][64*128] 32 KB [d][kv]
    float*    lbuf = (float*)(asmem + 65536);      // 256 f32 l/linv scratch

    const int tid  = threadIdx.x;
    const int wave = tid >> 6;
    const int lane = tid & 63;
    const int l31  = lane & 31;
    const int hi   = lane >> 5;
    const int l7   = lane & 7;
    const int qg   = wave & 3;             // q-row group (32 rows, 4 groups)
    const int kvq  = wave >> 2;            // kv quarter: 32 kv cols each
    const int h = blockIdx.x;              // head fastest -> XCD locality
    const int p = blockIdx.y;              // 0..7
    const int b = blockIdx.z;
    const int jH = 15 - p, jL = p;         // paired 128-row q-tiles
    const int TH = jH + 1;                 // 128-wide supertiles; TH+TL=17

    // staging: 1 K chunk + 1 V chunk per thread (1024 thr = full tile),
    // XOR source swizzle, linear LDS dest
    const uint16_t* kg;
    const uint16_t* vg;
    {
        int c = tid;                              // chunk 0..1023 (16 B)
        int rk = c >> 3, ck = c & 7;              // K: 128 rows x 8 chunks
        kg = K + ((size_t)(b * SEQ_T) + rk) * DMODEL + h * DHEAD + ((ck ^ (rk & 7)) * 8);
        int rv = c >> 4, cv = c & 15;             // V: 64 rows x 16 chunks
        int sv = (cv & 8) | ((cv & 7) ^ (rv & 7));
        vg = Vt + ((size_t)(b * 1024 + h * DHEAD + rv)) * 2048 + sv * 8;
    }

    int q0w = jH * 128 + qg * 32;          // this wave's q base
    bf16x8 qf[4];
    auto load_q = [&]() {
        const uint16_t* qb = Q + ((size_t)(b * SEQ_T) + q0w + l31) * DMODEL + h * DHEAD;
#pragma unroll
        for (int f = 0; f < 4; ++f)
            qf[f] = *(const bf16x8*)(qb + f * 16 + hi * 8);
    };
    load_q();

    floatx16 o[2];
#pragma unroll
    for (int dt = 0; dt < 2; ++dt) o[dt] = (floatx16)0.0f;
    float lac = 0.f;

    auto stage = [&](int kv0, int buf) {   // 2 global_load_lds per thread
        __builtin_amdgcn_global_load_lds(
            (const __attribute__((address_space(1))) void*)(kg + (size_t)kv0 * DMODEL),
            (__attribute__((address_space(3))) void*)(Ks0 + buf * 8192 + tid * 8), 16, 0, 0);
        __builtin_amdgcn_global_load_lds(
            (const __attribute__((address_space(1))) void*)(vg + kv0),
            (__attribute__((address_space(3))) void*)(Vs0 + buf * 8192 + tid * 8), 16, 0, 0);
    };

    // own + partner-half value (lane l <-> l^32) summed
    auto halfsum = [&](float x) -> float {
#if __has_builtin(__builtin_amdgcn_permlane32_swap)
        uint32x2 r = __builtin_amdgcn_permlane32_swap(__float_as_uint(x), __float_as_uint(x), false, false);
        return __uint_as_float(r.x) + __uint_as_float(r.y);
#else
        return x + __shfl_xor(x, 32, 64);
#endif
    };

    // merge kvq 3->2->1 partials into kvq 0 (fixed-base softmax => o,l
    // additive). o-scratch spans BOTH dead cur-buffers: Ks[cur] holds
    // qg 0-1 ([64 q][64 d] f32), Vs[cur] holds qg 2-3. All reads of buf
    // cur finished at the entry barrier; in-flight DMA targets cur^1;
    // next DMA into cur is issued only after the loop-bottom barrier.
    auto combine_store = [&](int cur) {
        __syncthreads();
        float* osc = (qg < 2) ? (float*)(Ks0 + cur * 8192)
                              : (float*)(Vs0 + cur * 8192);
        const int qoff = (qg & 1) * 32;
        float lt = halfsum(lac);
#pragma unroll
        for (int pass = 3; pass >= 1; --pass) {
            if (kvq == pass) {
                if (pass == 3) {
#pragma unroll
                    for (int dt = 0; dt < 2; ++dt)
#pragma unroll
                        for (int r = 0; r < 16; ++r) {
                            int row = (r & 3) + 8 * (r >> 2) + 4 * hi;
                            osc[(qoff + row) * 64 + dt * 32 + l31] = o[dt][r];
                        }
                    if (lane < 32) lbuf[qg * 32 + lane] = lt;
                } else {
#pragma unroll
                    for (int dt = 0; dt < 2; ++dt)
#pragma unroll
                        for (int r = 0; r < 16; ++r) {
                            int row = (r & 3) + 8 * (r >> 2) + 4 * hi;
                            osc[(qoff + row) * 64 + dt * 32 + l31] += o[dt][r];
                        }
                    if (lane < 32) lbuf[qg * 32 + lane] += lt;
                }
            }
            __syncthreads();
        }
        if (kvq == 0) {
            float ltot = lt + lbuf[qg * 32 + l31];
            if (lane < 32) lbuf[128 + qg * 32 + lane] = 1.f / ltot;
#pragma unroll
            for (int dt = 0; dt < 2; ++dt)
#pragma unroll
                for (int r = 0; r < 16; ++r) {
                    int row = (r & 3) + 8 * (r >> 2) + 4 * hi;
                    float ov = o[dt][r] + osc[(qoff + row) * 64 + dt * 32 + l31];
                    float li = lbuf[128 + qg * 32 + row];   // same-wave read
                    size_t addr = ((size_t)(b * SEQ_T) + q0w + row) * DMODEL + h * DHEAD + dt * 32 + l31;
                    ctx[addr] = f2bf(ov * li);
                }
        }
    };

    stage(0, 0);
    __syncthreads();

    for (int t = 0; t < 17; ++t) {
        const int cur = t & 1;
        const int kv0 = (t < TH ? t : t - TH) * 128;
        if (t + 1 < 17) {
            int tn = t + 1;
            stage((tn < TH ? tn : tn - TH) * 128, tn & 1);
        }
        const uint16_t* Kc = Ks0 + cur * 8192;
        const uint16_t* Vc = Vs0 + cur * 8192;
        const int kb = kv0 + kvq * 32;
        // QK^T swapped: S^T[k][q] = mfma(K, Q); lane: q = l31, k by reg
        floatx16 s = (floatx16)0.0f;
        __builtin_amdgcn_s_setprio(1);
#pragma unroll
        for (int f = 0; f < 4; ++f) {
            bf16x8 kf = *(const bf16x8*)&Kc[(kvq * 32 + l31) * 64 + (((2 * f + hi) ^ l7) << 3)];
            s = __builtin_amdgcn_mfma_f32_32x32x16_bf16(kf, qf[f], s, 0, 0, 0);
        }
        __builtin_amdgcn_s_setprio(0);
        if (kb + 31 > q0w) {               // causal mask (covers overhang)
            int qr = q0w + l31;
#pragma unroll
            for (int r = 0; r < 16; ++r) {
                int k = kb + (r & 3) + 8 * (r >> 2) + 4 * hi;
                if (k > qr) s[r] = -3e38f;
            }
        }
        // p = exp2(s) (scale folded into W_q); l rides a VALU sum.
        // exp2+pack fused (short live ranges).
        uint32_t d0[2], d1[2], d2[2], d3[2];
#pragma unroll
        for (int i = 0; i < 2; ++i) {
            float a, c2;
            a = __builtin_amdgcn_exp2f(s[2 * i]);      c2 = __builtin_amdgcn_exp2f(s[2 * i + 1]);
            lac += a + c2; d0[i] = pack2bf(a, c2);
            a = __builtin_amdgcn_exp2f(s[4 + 2 * i]);  c2 = __builtin_amdgcn_exp2f(s[4 + 2 * i + 1]);
            lac += a + c2; d1[i] = pack2bf(a, c2);
            a = __builtin_amdgcn_exp2f(s[8 + 2 * i]);  c2 = __builtin_amdgcn_exp2f(s[8 + 2 * i + 1]);
            lac += a + c2; d2[i] = pack2bf(a, c2);
            a = __builtin_amdgcn_exp2f(s[12 + 2 * i]); c2 = __builtin_amdgcn_exp2f(s[12 + 2 * i + 1]);
            lac += a + c2; d3[i] = pack2bf(a, c2);
        }
        // redistribute across lane halves -> PV A-frags (k contiguous)
        bf16x8 paf[2];
#if __has_builtin(__builtin_amdgcn_permlane32_swap)
        {
            uint32x2 r0 = __builtin_amdgcn_permlane32_swap(d0[0], d1[0], false, false);
            uint32x2 r1 = __builtin_amdgcn_permlane32_swap(d0[1], d1[1], false, false);
            union { uint32_t u[4]; bf16x8 v; } f0;
            f0.u[0] = r0.x; f0.u[1] = r1.x; f0.u[2] = r0.y; f0.u[3] = r1.y;
            paf[0] = f0.v;
            uint32x2 r2 = __builtin_amdgcn_permlane32_swap(d2[0], d3[0], false, false);
            uint32x2 r3 = __builtin_amdgcn_permlane32_swap(d2[1], d3[1], false, false);
            union { uint32_t u[4]; bf16x8 v; } f1;
            f1.u[0] = r2.x; f1.u[1] = r3.x; f1.u[2] = r2.y; f1.u[3] = r3.y;
            paf[1] = f1.v;
        }
#else
        {
            uint32_t s00 = __shfl_xor((int)d0[0], 32, 64), s01 = __shfl_xor((int)d0[1], 32, 64);
            uint32_t s10 = __shfl_xor((int)d1[0], 32, 64), s11 = __shfl_xor((int)d1[1], 32, 64);
            union { uint32_t u[4]; bf16x8 v; } f0;
            f0.u[0] = hi ? s10 : d0[0]; f0.u[1] = hi ? s11 : d0[1];
            f0.u[2] = hi ? d1[0] : s00; f0.u[3] = hi ? d1[1] : s01;
            paf[0] = f0.v;
            uint32_t s20 = __shfl_xor((int)d2[0], 32, 64), s21 = __shfl_xor((int)d2[1], 32, 64);
            uint32_t s30 = __shfl_xor((int)d3[0], 32, 64), s31 = __shfl_xor((int)d3[1], 32, 64);
            union { uint32_t u[4]; bf16x8 v; } f1;
            f1.u[0] = hi ? s30 : d2[0]; f1.u[1] = hi ? s31 : d2[1];
            f1.u[2] = hi ? d3[0] : s20; f1.u[3] = hi ? d3[1] : s21;
            paf[1] = f1.v;
        }
#endif
        // PV: O[q][d] += P x V  (A = in-reg P, B = V^T rows from LDS)
        __builtin_amdgcn_s_setprio(1);
#pragma unroll
        for (int f = 0; f < 2; ++f)
#pragma unroll
            for (int dt = 0; dt < 2; ++dt) {
                bf16x8 vf = *(const bf16x8*)&Vc[(dt * 32 + l31) * 128 + (((kvq * 4 + 2 * f + hi) ^ l7) << 3)];
                o[dt] = __builtin_amdgcn_mfma_f32_32x32x16_bf16(paf[f], vf, o[dt], 0, 0, 0);
            }
        __builtin_amdgcn_s_setprio(0);
        if (t == TH - 1) {                 // high q-tile done: merge + store
            combine_store(cur);
            q0w = jL * 128 + qg * 32;
            load_q();
#pragma unroll
            for (int dt = 0; dt < 2; ++dt) o[dt] = (floatx16)0.0f;
            lac = 0.f;
        }
        if (t + 1 < 17) __syncthreads();   // next buffer staged & landed
    }
    combine_store(0);                      // t=16 -> cur=0
}

extern "C" void kernel_launch(void* const* d_in, const int* in_sizes, int n_in,
                              void* d_out, int out_size, void* d_ws, size_t ws_size,
                              hipStream_t stream) {
    const float* x  = (const float*)d_in[0];
    const float* Wq = (const float*)d_in[1];
    const float* Wk = (const float*)d_in[2];
    const float* Wv = (const float*)d_in[3];
    const float* Wo = (const float*)d_in[4];
    const float* bo = (const float*)d_in[5];
    float* out = (float*)d_out;

    char* ws = (char*)d_ws;
    const size_t SZ_X = (size_t)4096 * DMODEL * 2;   // 8 MB
    const size_t SZ_W = (size_t)DMODEL * DMODEL * 2; // 2 MB
    size_t off = 0;
    uint16_t* xb  = (uint16_t*)(ws + off); off += SZ_X;
    uint16_t* wqt = (uint16_t*)(ws + off); off += SZ_W;
    uint16_t* wkt = (uint16_t*)(ws + off); off += SZ_W;
    uint16_t* wvt = (uint16_t*)(ws + off); off += SZ_W;
    uint16_t* wot = (uint16_t*)(ws + off); off += SZ_W;
    uint16_t* Qb  = (uint16_t*)(ws + off); off += SZ_X;
    uint16_t* Kb  = (uint16_t*)(ws + off); off += SZ_X;
    uint16_t* Vtb = (uint16_t*)(ws + off); off += SZ_X;  // per-head transposed V
    uint16_t* Cb  = (uint16_t*)(ws + off); off += SZ_X;
    (void)ws_size; (void)in_sizes; (void)n_in; (void)out_size;

    mha_cvt<<<dim3(16, 16, 5), 256, 0, stream>>>(x, xb, Wq, Wk, Wv, Wo, wqt, wkt, wvt, wot);
    mha_gemm_qkv<<<dim3(8, 64, 3), 256, 24576, stream>>>(xb, wqt, wkt, wvt, Qb, Kb, Vtb);
    mha_attn_mfma<<<dim3(NHEAD, 8, 2), 1024, 66560, stream>>>(Qb, Kb, Vtb, Cb);
    mha_gemm_out<<<dim3(8, 64), 512, 24576, stream>>>(Cb, wot, out, bo);
}

// Round 9
// 176.753 us; speedup vs baseline: 1.1552x; 1.0240x over previous
//
#include <hip/hip_runtime.h>
#include <hip/hip_bf16.h>
#include <cstdint>

// Problem constants: B=2, T=2048, D_IN=D_OUT=1024, H=16, DH=64
#define SEQ_T 2048
#define DMODEL 1024
#define NHEAD 16
#define DHEAD 64

typedef __attribute__((ext_vector_type(8))) __bf16 bf16x8;
typedef __attribute__((ext_vector_type(4))) float floatx4;
typedef __attribute__((ext_vector_type(16))) float floatx16;
typedef __attribute__((ext_vector_type(2))) unsigned uint32x2;

static __device__ __forceinline__ uint16_t f2bf(float f) {
    union { float f; uint32_t u; } v; v.f = f;
    uint32_t r = v.u + 0x7FFFu + ((v.u >> 16) & 1u);   // RNE
    return (uint16_t)(r >> 16);
}

static __device__ __forceinline__ uint32_t pack2bf(float a, float b) {
    // compiler fuses paired casts into v_cvt_pk_bf16_f32 (m240: faster than hand asm)
    union { __bf16 h[2]; uint32_t u; } p;
    p.h[0] = (__bf16)a; p.h[1] = (__bf16)b;
    return p.u;
}

// -------- merged fp32->bf16 converts: z<4 weight transpose, z==4 x --------
// W_q (z==0) pre-scaled by 0.125*log2(e): QK^T emits s*C directly, so the
// attention softmax is a single raw v_exp_f32 (__builtin_amdgcn_exp2f).
__global__ void mha_cvt(const float* __restrict__ x, uint16_t* __restrict__ xb,
                        const float* __restrict__ W0, const float* __restrict__ W1,
                        const float* __restrict__ W2, const float* __restrict__ W3,
                        uint16_t* __restrict__ T0, uint16_t* __restrict__ T1,
                        uint16_t* __restrict__ T2, uint16_t* __restrict__ T3) {
    if (blockIdx.z == 4) {
        int base = (blockIdx.y * 16 + blockIdx.x) * 256 + threadIdx.x;
#pragma unroll
        for (int i = 0; i < 16; ++i) {
            int idx = base + i * 65536;
            float4 f = ((const float4*)x)[idx];
            union { uint16_t u[4]; uint64_t v; } o;
            o.u[0] = f2bf(f.x); o.u[1] = f2bf(f.y); o.u[2] = f2bf(f.z); o.u[3] = f2bf(f.w);
            ((uint64_t*)xb)[idx] = o.v;
        }
        return;
    }
    const float* W; uint16_t* Tt; float sc;
    switch (blockIdx.z) {
        case 0: W = W0; Tt = T0; sc = 0.125f * 1.44269504089f; break;
        case 1: W = W1; Tt = T1; sc = 1.f; break;
        case 2: W = W2; Tt = T2; sc = 1.f; break;
        default: W = W3; Tt = T3; sc = 1.f; break;
    }
    __shared__ float tile[64][65];
    const int c  = threadIdx.x & 63;
    const int r0 = threadIdx.x >> 6;
    const int R0 = blockIdx.y * 64, C0 = blockIdx.x * 64;
#pragma unroll
    for (int rr = 0; rr < 16; ++rr) {
        int r = r0 + rr * 4;
        tile[r][c] = W[(size_t)(R0 + r) * DMODEL + C0 + c];
    }
    __syncthreads();
#pragma unroll
    for (int rr = 0; rr < 16; ++rr) {
        int r = r0 + rr * 4;
        Tt[(size_t)(C0 + r) * DMODEL + R0 + c] = f2bf(tile[c][r] * sc);
    }
}

// ------ bf16 MFMA GEMM, 64M x 128N tile, BK=64, B^T input, swizzled ------
// (R10/R12-proven shape; qkv grid 1536 = 6 blocks/CU @ 24 KB dynamic LDS.
// R5's 128x128 retile was neutral-to-negative -> reverted to this config.)
// Swizzle: row r slot q' holds source sub-chunk q'^(r&7) -> 2-way-only.
// MODE 0: bf16 row-major out. MODE 1: Vt[(b*1024+col)*2048+t] via LDS
// transpose reusing staging smem.
template<int MODE>
__device__ __forceinline__ void gemm_bk64_body(
    const uint16_t* __restrict__ A, const uint16_t* __restrict__ Bt,
    uint16_t* __restrict__ outB) {
    const int K = DMODEL, N = DMODEL;
    extern __shared__ char smem[];                  // 24576 B dynamic
    uint16_t* As = (uint16_t*)smem;                 // [64][64]  8 KB
    uint16_t* Bs = (uint16_t*)(smem + 8192);        // [128][64] 16 KB
    const int tid  = threadIdx.x;
    const int wave = tid >> 6;
    const int lane = tid & 63;
    const int m0 = blockIdx.y * 64;
    const int n0 = blockIdx.x * 128;
    const int lr   = lane & 15;
    const int quad = lane >> 4;

    floatx4 acc[4][2];
#pragma unroll
    for (int i = 0; i < 4; ++i)
#pragma unroll
        for (int j = 0; j < 2; ++j) acc[i][j] = (floatx4)0.0f;

    for (int k0 = 0; k0 < K; k0 += 64) {
#pragma unroll
        for (int i = 0; i < 2; ++i) {               // A: 512 chunks (16B)
            int c = i * 256 + tid;
            int r = c >> 3, s = (c & 7) ^ (r & 7);
            const uint16_t* g = A + (size_t)(m0 + r) * K + k0 + s * 8;
            __builtin_amdgcn_global_load_lds((const __attribute__((address_space(1))) void*)g,
                                             (__attribute__((address_space(3))) void*)(As + (size_t)c * 8), 16, 0, 0);
        }
#pragma unroll
        for (int i = 0; i < 4; ++i) {               // B: 1024 chunks
            int c = i * 256 + tid;
            int r = c >> 3, s = (c & 7) ^ (r & 7);
            const uint16_t* g = Bt + (size_t)(n0 + r) * K + k0 + s * 8;
            __builtin_amdgcn_global_load_lds((const __attribute__((address_space(1))) void*)g,
                                             (__attribute__((address_space(3))) void*)(Bs + (size_t)c * 8), 16, 0, 0);
        }
        __syncthreads();
#pragma unroll
        for (int ks = 0; ks < 2; ++ks) {            // two 32-wide k-halves
            bf16x8 af[4], bfr[2];
#pragma unroll
            for (int mi = 0; mi < 4; ++mi) {
                int row = mi * 16 + lr;
                af[mi] = *(const bf16x8*)&As[row * 64 + (((ks * 4 + quad) ^ (row & 7)) << 3)];
            }
#pragma unroll
            for (int ni = 0; ni < 2; ++ni) {
                int row = wave * 32 + ni * 16 + lr;
                bfr[ni] = *(const bf16x8*)&Bs[row * 64 + (((ks * 4 + quad) ^ (row & 7)) << 3)];
            }
#pragma unroll
            for (int mi = 0; mi < 4; ++mi)
#pragma unroll
                for (int ni = 0; ni < 2; ++ni)
                    acc[mi][ni] = __builtin_amdgcn_mfma_f32_16x16x32_bf16(af[mi], bfr[ni], acc[mi][ni], 0, 0, 0);
        }
        __syncthreads();
    }
    if constexpr (MODE == 1) {
        uint16_t* Ct = (uint16_t*)smem;             // [128][72], 18.4 KB
        const int bb = m0 >> 11, t0 = m0 & 2047;
#pragma unroll
        for (int mi = 0; mi < 4; ++mi)
#pragma unroll
            for (int ni = 0; ni < 2; ++ni) {
                int cl = wave * 32 + ni * 16 + lr;
                int tl = mi * 16 + quad * 4;
                int tls = tl ^ ((cl & 3) << 4);     // 2-way-only bank pattern
                union { uint16_t u[4]; uint64_t v8; } pk;
#pragma unroll
                for (int r = 0; r < 4; ++r) pk.u[r] = f2bf(acc[mi][ni][r]);
                *(uint64_t*)&Ct[cl * 72 + tls] = pk.v8;
            }
        __syncthreads();
#pragma unroll
        for (int k = 0; k < 4; ++k) {
            int c = k * 256 + tid;                  // 1024 chunks of 16B
            int cl = c >> 3, off = (c & 7) * 8;
            int offs = off ^ ((cl & 3) << 4);
            uint4 v = *(const uint4*)&Ct[cl * 72 + offs];
            *(uint4*)&outB[((size_t)(bb * 1024 + n0 + cl)) * 2048 + t0 + off] = v;
        }
    } else {
#pragma unroll
        for (int mi = 0; mi < 4; ++mi)
#pragma unroll
            for (int ni = 0; ni < 2; ++ni) {
                int col = n0 + wave * 32 + ni * 16 + lr;
#pragma unroll
                for (int r = 0; r < 4; ++r) {
                    int row = m0 + mi * 16 + quad * 4 + r;
                    outB[(size_t)row * N + col] = f2bf(acc[mi][ni][r]);
                }
            }
    }
}

__global__ __launch_bounds__(256) void mha_gemm_qkv(
    const uint16_t* __restrict__ A,
    const uint16_t* __restrict__ Wq, const uint16_t* __restrict__ Wk, const uint16_t* __restrict__ Wv,
    uint16_t* __restrict__ Q, uint16_t* __restrict__ K, uint16_t* __restrict__ Vt) {
    switch (blockIdx.z) {
        case 0:  gemm_bk64_body<0>(A, Wq, Q);  break;
        case 1:  gemm_bk64_body<0>(A, Wk, K);  break;
        default: gemm_bk64_body<1>(A, Wv, Vt); break;
    }
}

// ---- out-projection GEMM: 64M x 128N, BK=64, 512 thr / 8 waves ----
// (R14-best config: wave-tile 32x32, grid (8,64) = 2 blocks/CU x 8 waves
// = 16 waves/CU. R15's 64x64 retile regressed ~3.6 µs — reverted.)
__global__ __launch_bounds__(512) void mha_gemm_out(
    const uint16_t* __restrict__ A, const uint16_t* __restrict__ Wot,
    float* __restrict__ out, const float* __restrict__ bias) {
    const int K = DMODEL, N = DMODEL;
    extern __shared__ char smem[];                  // 24576 B dynamic
    uint16_t* As = (uint16_t*)smem;                 // [64][64]  8 KB
    uint16_t* Bs = (uint16_t*)(smem + 8192);        // [128][64] 16 KB
    const int tid  = threadIdx.x;
    const int wave = tid >> 6;
    const int lane = tid & 63;
    const int m0 = blockIdx.y * 64;
    const int n0 = blockIdx.x * 128;
    const int lr   = lane & 15;
    const int quad = lane >> 4;
    const int wm = wave >> 2, wn = wave & 3;        // 2m x 4n wave grid

    floatx4 acc[2][2];
#pragma unroll
    for (int i = 0; i < 2; ++i)
#pragma unroll
        for (int j = 0; j < 2; ++j) acc[i][j] = (floatx4)0.0f;

    for (int k0 = 0; k0 < K; k0 += 64) {
        {                                           // A: 512 chunks
            int c = tid;
            int r = c >> 3, s = (c & 7) ^ (r & 7);
            const uint16_t* g = A + (size_t)(m0 + r) * K + k0 + s * 8;
            __builtin_amdgcn_global_load_lds((const __attribute__((address_space(1))) void*)g,
                                             (__attribute__((address_space(3))) void*)(As + (size_t)c * 8), 16, 0, 0);
        }
#pragma unroll
        for (int i = 0; i < 2; ++i) {               // B: 1024 chunks
            int c = i * 512 + tid;
            int r = c >> 3, s = (c & 7) ^ (r & 7);
            const uint16_t* g = Wot + (size_t)(n0 + r) * K + k0 + s * 8;
            __builtin_amdgcn_global_load_lds((const __attribute__((address_space(1))) void*)g,
                                             (__attribute__((address_space(3))) void*)(Bs + (size_t)c * 8), 16, 0, 0);
        }
        __syncthreads();
#pragma unroll
        for (int ks = 0; ks < 2; ++ks) {
            bf16x8 af[2], bfr[2];
#pragma unroll
            for (int mi = 0; mi < 2; ++mi) {
                int row = wm * 32 + mi * 16 + lr;
                af[mi] = *(const bf16x8*)&As[row * 64 + (((ks * 4 + quad) ^ (row & 7)) << 3)];
            }
#pragma unroll
            for (int ni = 0; ni < 2; ++ni) {
                int row = wn * 32 + ni * 16 + lr;
                bfr[ni] = *(const bf16x8*)&Bs[row * 64 + (((ks * 4 + quad) ^ (row & 7)) << 3)];
            }
#pragma unroll
            for (int mi = 0; mi < 2; ++mi)
#pragma unroll
                for (int ni = 0; ni < 2; ++ni)
                    acc[mi][ni] = __builtin_amdgcn_mfma_f32_16x16x32_bf16(af[mi], bfr[ni], acc[mi][ni], 0, 0, 0);
        }
        __syncthreads();
    }
#pragma unroll
    for (int mi = 0; mi < 2; ++mi)
#pragma unroll
        for (int ni = 0; ni < 2; ++ni) {
            int col = n0 + wn * 32 + ni * 16 + lr;
            float bv = bias[col];
#pragma unroll
            for (int r = 0; r < 4; ++r) {
                int row = m0 + wm * 32 + mi * 16 + quad * 4 + r;
                out[(size_t)row * N + col] = acc[mi][ni][r] + bv;
            }
        }
}

// ---------------- MFMA flash attention (causal, fixed-base softmax) -------
// R9 = R8 geometry with the spill bug fixed. R8's counters: VGPR forced
// to 64 + scratch spills (WRITE_SIZE 8->40 MB) because __launch_bounds__
// (1024) with no min-waves arg makes the compiler target 8-waves/EU.
// R6 failed the same way with an explicit ",4" (also -> 64 VGPR). The
// only spill-free settings measured are (512,2) -> 92 VGPR and plain
// 256-thr -> 120. Fix: __launch_bounds__(1024, 1) — min 1 wave/EU sets
// the full 512-VGPR budget; the allocator takes ~92-120 as it did under
// (512,2); achieved occupancy is then LDS-limited to exactly 1 block =
// 16 waves/CU, which is what this geometry wants.
// Geometry (R8): ONE 1024-thread block (16 waves = 4 qg x 4 kvq) per CU;
// grid (16 h, 8 p, 2 b) = 256 = 1 block/CU. q-tile 128, pairs jH=15-p /
// jL=p; kv supertile 128; TH=jH+1, TH+TL=17 iters. Staged 544 KB/CU =
// half of the q-tile-64 variants. LDS 65 KB dynamic: Ks[2][128x64] 32K +
// Vs[2][64x128] 32K + lbuf 1K. This completes the clean 2x2 of
// {waves/CU} x {staged bytes}: R1=1.09MB/16w=43.8, R2=1.09MB/8w=44.6,
// R3=544KB/8w=41.5, R9=544KB/16w=?
__global__ __launch_bounds__(1024, 1) void mha_attn_mfma(
    const uint16_t* __restrict__ Q, const uint16_t* __restrict__ K,
    const uint16_t* __restrict__ Vt, uint16_t* __restrict__ ctx) {
    extern __shared__ char asmem[];
    uint16_t* Ks0 = (uint16_t*)asmem;              // [2][128*64] 32 KB [kv][d]
    uint16_t* Vs0 = (uint16_t*)(asmem + 32768);    // [2][64*128] 32 KB [d][kv]
    float*    lbuf = (float*)(asmem + 65536);      // 256 f32 l/linv scratch

    const int tid  = threadIdx.x;
    const int wave = tid >> 6;
    const int lane = tid & 63;
    const int l31  = lane & 31;
    const int hi   = lane >> 5;
    const int l7   = lane & 7;
    const int qg   = wave & 3;             // q-row group (32 rows, 4 groups)
    const int kvq  = wave >> 2;            // kv quarter: 32 kv cols each
    const int h = blockIdx.x;              // head fastest -> XCD locality
    const int p = blockIdx.y;              // 0..7
    const int b = blockIdx.z;
    const int jH = 15 - p, jL = p;         // paired 128-row q-tiles
    const int TH = jH + 1;                 // 128-wide supertiles; TH+TL=17

    // staging: 1 K chunk + 1 V chunk per thread (1024 thr = full tile),
    // XOR source swizzle, linear LDS dest
    const uint16_t* kg;
    const uint16_t* vg;
    {
        int c = tid;                              // chunk 0..1023 (16 B)
        int rk = c >> 3, ck = c & 7;              // K: 128 rows x 8 chunks
        kg = K + ((size_t)(b * SEQ_T) + rk) * DMODEL + h * DHEAD + ((ck ^ (rk & 7)) * 8);
        int rv = c >> 4, cv = c & 15;             // V: 64 rows x 16 chunks
        int sv = (cv & 8) | ((cv & 7) ^ (rv & 7));
        vg = Vt + ((size_t)(b * 1024 + h * DHEAD + rv)) * 2048 + sv * 8;
    }

    int q0w = jH * 128 + qg * 32;          // this wave's q base
    bf16x8 qf[4];
    auto load_q = [&]() {
        const uint16_t* qb = Q + ((size_t)(b * SEQ_T) + q0w + l31) * DMODEL + h * DHEAD;
#pragma unroll
        for (int f = 0; f < 4; ++f)
            qf[f] = *(const bf16x8*)(qb + f * 16 + hi * 8);
    };
    load_q();

    floatx16 o[2];
#pragma unroll
    for (int dt = 0; dt < 2; ++dt) o[dt] = (floatx16)0.0f;
    float lac = 0.f;

    auto stage = [&](int kv0, int buf) {   // 2 global_load_lds per thread
        __builtin_amdgcn_global_load_lds(
            (const __attribute__((address_space(1))) void*)(kg + (size_t)kv0 * DMODEL),
            (__attribute__((address_space(3))) void*)(Ks0 + buf * 8192 + tid * 8), 16, 0, 0);
        __builtin_amdgcn_global_load_lds(
            (const __attribute__((address_space(1))) void*)(vg + kv0),
            (__attribute__((address_space(3))) void*)(Vs0 + buf * 8192 + tid * 8), 16, 0, 0);
    };

    // own + partner-half value (lane l <-> l^32) summed
    auto halfsum = [&](float x) -> float {
#if __has_builtin(__builtin_amdgcn_permlane32_swap)
        uint32x2 r = __builtin_amdgcn_permlane32_swap(__float_as_uint(x), __float_as_uint(x), false, false);
        return __uint_as_float(r.x) + __uint_as_float(r.y);
#else
        return x + __shfl_xor(x, 32, 64);
#endif
    };

    // merge kvq 3->2->1 partials into kvq 0 (fixed-base softmax => o,l
    // additive). o-scratch spans BOTH dead cur-buffers: Ks[cur] holds
    // qg 0-1 ([64 q][64 d] f32), Vs[cur] holds qg 2-3. All reads of buf
    // cur finished at the entry barrier; in-flight DMA targets cur^1;
    // next DMA into cur is issued only after the loop-bottom barrier.
    auto combine_store = [&](int cur) {
        __syncthreads();
        float* osc = (qg < 2) ? (float*)(Ks0 + cur * 8192)
                              : (float*)(Vs0 + cur * 8192);
        const int qoff = (qg & 1) * 32;
        float lt = halfsum(lac);
#pragma unroll
        for (int pass = 3; pass >= 1; --pass) {
            if (kvq == pass) {
                if (pass == 3) {
#pragma unroll
                    for (int dt = 0; dt < 2; ++dt)
#pragma unroll
                        for (int r = 0; r < 16; ++r) {
                            int row = (r & 3) + 8 * (r >> 2) + 4 * hi;
                            osc[(qoff + row) * 64 + dt * 32 + l31] = o[dt][r];
                        }
                    if (lane < 32) lbuf[qg * 32 + lane] = lt;
                } else {
#pragma unroll
                    for (int dt = 0; dt < 2; ++dt)
#pragma unroll
                        for (int r = 0; r < 16; ++r) {
                            int row = (r & 3) + 8 * (r >> 2) + 4 * hi;
                            osc[(qoff + row) * 64 + dt * 32 + l31] += o[dt][r];
                        }
                    if (lane < 32) lbuf[qg * 32 + lane] += lt;
                }
            }
            __syncthreads();
        }
        if (kvq == 0) {
            float ltot = lt + lbuf[qg * 32 + l31];
            if (lane < 32) lbuf[128 + qg * 32 + lane] = 1.f / ltot;
#pragma unroll
            for (int dt = 0; dt < 2; ++dt)
#pragma unroll
                for (int r = 0; r < 16; ++r) {
                    int row = (r & 3) + 8 * (r >> 2) + 4 * hi;
                    float ov = o[dt][r] + osc[(qoff + row) * 64 + dt * 32 + l31];
                    float li = lbuf[128 + qg * 32 + row];   // same-wave read
                    size_t addr = ((size_t)(b * SEQ_T) + q0w + row) * DMODEL + h * DHEAD + dt * 32 + l31;
                    ctx[addr] = f2bf(ov * li);
                }
        }
    };

    stage(0, 0);
    __syncthreads();

    for (int t = 0; t < 17; ++t) {
        const int cur = t & 1;
        const int kv0 = (t < TH ? t : t - TH) * 128;
        if (t + 1 < 17) {
            int tn = t + 1;
            stage((tn < TH ? tn : tn - TH) * 128, tn & 1);
        }
        const uint16_t* Kc = Ks0 + cur * 8192;
        const uint16_t* Vc = Vs0 + cur * 8192;
        const int kb = kv0 + kvq * 32;
        // QK^T swapped: S^T[k][q] = mfma(K, Q); lane: q = l31, k by reg
        floatx16 s = (floatx16)0.0f;
        __builtin_amdgcn_s_setprio(1);
#pragma unroll
        for (int f = 0; f < 4; ++f) {
            bf16x8 kf = *(const bf16x8*)&Kc[(kvq * 32 + l31) * 64 + (((2 * f + hi) ^ l7) << 3)];
            s = __builtin_amdgcn_mfma_f32_32x32x16_bf16(kf, qf[f], s, 0, 0, 0);
        }
        __builtin_amdgcn_s_setprio(0);
        if (kb + 31 > q0w) {               // causal mask (covers overhang)
            int qr = q0w + l31;
#pragma unroll
            for (int r = 0; r < 16; ++r) {
                int k = kb + (r & 3) + 8 * (r >> 2) + 4 * hi;
                if (k > qr) s[r] = -3e38f;
            }
        }
        // p = exp2(s) (scale folded into W_q); l rides a VALU sum.
        // exp2+pack fused (short live ranges).
        uint32_t d0[2], d1[2], d2[2], d3[2];
#pragma unroll
        for (int i = 0; i < 2; ++i) {
            float a, c2;
            a = __builtin_amdgcn_exp2f(s[2 * i]);      c2 = __builtin_amdgcn_exp2f(s[2 * i + 1]);
            lac += a + c2; d0[i] = pack2bf(a, c2);
            a = __builtin_amdgcn_exp2f(s[4 + 2 * i]);  c2 = __builtin_amdgcn_exp2f(s[4 + 2 * i + 1]);
            lac += a + c2; d1[i] = pack2bf(a, c2);
            a = __builtin_amdgcn_exp2f(s[8 + 2 * i]);  c2 = __builtin_amdgcn_exp2f(s[8 + 2 * i + 1]);
            lac += a + c2; d2[i] = pack2bf(a, c2);
            a = __builtin_amdgcn_exp2f(s[12 + 2 * i]); c2 = __builtin_amdgcn_exp2f(s[12 + 2 * i + 1]);
            lac += a + c2; d3[i] = pack2bf(a, c2);
        }
        // redistribute across lane halves -> PV A-frags (k contiguous)
        bf16x8 paf[2];
#if __has_builtin(__builtin_amdgcn_permlane32_swap)
        {
            uint32x2 r0 = __builtin_amdgcn_permlane32_swap(d0[0], d1[0], false, false);
            uint32x2 r1 = __builtin_amdgcn_permlane32_swap(d0[1], d1[1], false, false);
            union { uint32_t u[4]; bf16x8 v; } f0;
            f0.u[0] = r0.x; f0.u[1] = r1.x; f0.u[2] = r0.y; f0.u[3] = r1.y;
            paf[0] = f0.v;
            uint32x2 r2 = __builtin_amdgcn_permlane32_swap(d2[0], d3[0], false, false);
            uint32x2 r3 = __builtin_amdgcn_permlane32_swap(d2[1], d3[1], false, false);
            union { uint32_t u[4]; bf16x8 v; } f1;
            f1.u[0] = r2.x; f1.u[1] = r3.x; f1.u[2] = r2.y; f1.u[3] = r3.y;
            paf[1] = f1.v;
        }
#else
        {
            uint32_t s00 = __shfl_xor((int)d0[0], 32, 64), s01 = __shfl_xor((int)d0[1], 32, 64);
            uint32_t s10 = __shfl_xor((int)d1[0], 32, 64), s11 = __shfl_xor((int)d1[1], 32, 64);
            union { uint32_t u[4]; bf16x8 v; } f0;
            f0.u[0] = hi ? s10 : d0[0]; f0.u[1] = hi ? s11 : d0[1];
            f0.u[2] = hi ? d1[0] : s00; f0.u[3] = hi ? d1[1] : s01;
            paf[0] = f0.v;
            uint32_t s20 = __shfl_xor((int)d2[0], 32, 64), s21 = __shfl_xor((int)d2[1], 32, 64);
            uint32_t s30 = __shfl_xor((int)d3[0], 32, 64), s31 = __shfl_xor((int)d3[1], 32, 64);
            union { uint32_t u[4]; bf16x8 v; } f1;
            f1.u[0] = hi ? s30 : d2[0]; f1.u[1] = hi ? s31 : d2[1];
            f1.u[2] = hi ? d3[0] : s20; f1.u[3] = hi ? d3[1] : s21;
            paf[1] = f1.v;
        }
#endif
        // PV: O[q][d] += P x V  (A = in-reg P, B = V^T rows from LDS)
        __builtin_amdgcn_s_setprio(1);
#pragma unroll
        for (int f = 0; f < 2; ++f)
#pragma unroll
            for (int dt = 0; dt < 2; ++dt) {
                bf16x8 vf = *(const bf16x8*)&Vc[(dt * 32 + l31) * 128 + (((kvq * 4 + 2 * f + hi) ^ l7) << 3)];
                o[dt] = __builtin_amdgcn_mfma_f32_32x32x16_bf16(paf[f], vf, o[dt], 0, 0, 0);
            }
        __builtin_amdgcn_s_setprio(0);
        if (t == TH - 1) {                 // high q-tile done: merge + store
            combine_store(cur);
            q0w = jL * 128 + qg * 32;
            load_q();
#pragma unroll
            for (int dt = 0; dt < 2; ++dt) o[dt] = (floatx16)0.0f;
            lac = 0.f;
        }
        if (t + 1 < 17) __syncthreads();   // next buffer staged & landed
    }
    combine_store(0);                      // t=16 -> cur=0
}

extern "C" void kernel_launch(void* const* d_in, const int* in_sizes, int n_in,
                              void* d_out, int out_size, void* d_ws, size_t ws_size,
                              hipStream_t stream) {
    const float* x  = (const float*)d_in[0];
    const float* Wq = (const float*)d_in[1];
    const float* Wk = (const float*)d_in[2];
    const float* Wv = (const float*)d_in[3];
    const float* Wo = (const float*)d_in[4];
    const float* bo = (const float*)d_in[5];
    float* out = (float*)d_out;

    char* ws = (char*)d_ws;
    const size_t SZ_X = (size_t)4096 * DMODEL * 2;   // 8 MB
    const size_t SZ_W = (size_t)DMODEL * DMODEL * 2; // 2 MB
    size_t off = 0;
    uint16_t* xb  = (uint16_t*)(ws + off); off += SZ_X;
    uint16_t* wqt = (uint16_t*)(ws + off); off += SZ_W;
    uint16_t* wkt = (uint16_t*)(ws + off); off += SZ_W;
    uint16_t* wvt = (uint16_t*)(ws + off); off += SZ_W;
    uint16_t* wot = (uint16_t*)(ws + off); off += SZ_W;
    uint16_t* Qb  = (uint16_t*)(ws + off); off += SZ_X;
    uint16_t* Kb  = (uint16_t*)(ws + off); off += SZ_X;
    uint16_t* Vtb = (uint16_t*)(ws + off); off += SZ_X;  // per-head transposed V
    uint16_t* Cb  = (uint16_t*)(ws + off); off += SZ_X;
    (void)ws_size; (void)in_sizes; (void)n_in; (void)out_size;

    mha_cvt<<<dim3(16, 16, 5), 256, 0, stream>>>(x, xb, Wq, Wk, Wv, Wo, wqt, wkt, wvt, wot);
    mha_gemm_qkv<<<dim3(8, 64, 3), 256, 24576, stream>>>(xb, wqt, wkt, wvt, Qb, Kb, Vtb);
    mha_attn_mfma<<<dim3(NHEAD, 8, 2), 1024, 66560, stream>>>(Qb, Kb, Vtb, Cb);
    mha_gemm_out<<<dim3(8, 64), 512, 24576, stream>>>(Cb, wot, out, bo);
}

// Round 10
// 168.900 us; speedup vs baseline: 1.2089x; 1.0465x over previous
//
#include <hip/hip_runtime.h>
#include <hip/hip_bf16.h>
#include <cstdint>

// Problem constants: B=2, T=2048, D_IN=D_OUT=1024, H=16, DH=64
#define SEQ_T 2048
#define DMODEL 1024
#define NHEAD 16
#define DHEAD 64

typedef __attribute__((ext_vector_type(8))) __bf16 bf16x8;
typedef __attribute__((ext_vector_type(4))) float floatx4;
typedef __attribute__((ext_vector_type(16))) float floatx16;
typedef __attribute__((ext_vector_type(2))) unsigned uint32x2;

static __device__ __forceinline__ uint16_t f2bf(float f) {
    union { float f; uint32_t u; } v; v.f = f;
    uint32_t r = v.u + 0x7FFFu + ((v.u >> 16) & 1u);   // RNE
    return (uint16_t)(r >> 16);
}

static __device__ __forceinline__ uint32_t pack2bf(float a, float b) {
    // compiler fuses paired casts into v_cvt_pk_bf16_f32 (m240: faster than hand asm)
    union { __bf16 h[2]; uint32_t u; } p;
    p.h[0] = (__bf16)a; p.h[1] = (__bf16)b;
    return p.u;
}

// -------- merged fp32->bf16 converts: z<4 weight transpose, z==4 x --------
// W_q (z==0) pre-scaled by 0.125*log2(e): QK^T emits s*C directly, so the
// attention softmax is a single raw v_exp_f32 (__builtin_amdgcn_exp2f).
__global__ void mha_cvt(const float* __restrict__ x, uint16_t* __restrict__ xb,
                        const float* __restrict__ W0, const float* __restrict__ W1,
                        const float* __restrict__ W2, const float* __restrict__ W3,
                        uint16_t* __restrict__ T0, uint16_t* __restrict__ T1,
                        uint16_t* __restrict__ T2, uint16_t* __restrict__ T3) {
    if (blockIdx.z == 4) {
        int base = (blockIdx.y * 16 + blockIdx.x) * 256 + threadIdx.x;
#pragma unroll
        for (int i = 0; i < 16; ++i) {
            int idx = base + i * 65536;
            float4 f = ((const float4*)x)[idx];
            union { uint16_t u[4]; uint64_t v; } o;
            o.u[0] = f2bf(f.x); o.u[1] = f2bf(f.y); o.u[2] = f2bf(f.z); o.u[3] = f2bf(f.w);
            ((uint64_t*)xb)[idx] = o.v;
        }
        return;
    }
    const float* W; uint16_t* Tt; float sc;
    switch (blockIdx.z) {
        case 0: W = W0; Tt = T0; sc = 0.125f * 1.44269504089f; break;
        case 1: W = W1; Tt = T1; sc = 1.f; break;
        case 2: W = W2; Tt = T2; sc = 1.f; break;
        default: W = W3; Tt = T3; sc = 1.f; break;
    }
    __shared__ float tile[64][65];
    const int c  = threadIdx.x & 63;
    const int r0 = threadIdx.x >> 6;
    const int R0 = blockIdx.y * 64, C0 = blockIdx.x * 64;
#pragma unroll
    for (int rr = 0; rr < 16; ++rr) {
        int r = r0 + rr * 4;
        tile[r][c] = W[(size_t)(R0 + r) * DMODEL + C0 + c];
    }
    __syncthreads();
#pragma unroll
    for (int rr = 0; rr < 16; ++rr) {
        int r = r0 + rr * 4;
        Tt[(size_t)(C0 + r) * DMODEL + R0 + c] = f2bf(tile[c][r] * sc);
    }
}

// ------ bf16 MFMA GEMM, 64M x 128N tile, BK=64, B^T input, swizzled ------
// (R10/R12-proven shape; qkv grid 1536 = 6 blocks/CU @ 24 KB dynamic LDS.
// R5's 128x128 retile was neutral-to-negative -> reverted to this config.)
// Swizzle: row r slot q' holds source sub-chunk q'^(r&7) -> 2-way-only.
// MODE 0: bf16 row-major out. MODE 1: Vt[(b*1024+col)*2048+t] via LDS
// transpose reusing staging smem.
template<int MODE>
__device__ __forceinline__ void gemm_bk64_body(
    const uint16_t* __restrict__ A, const uint16_t* __restrict__ Bt,
    uint16_t* __restrict__ outB) {
    const int K = DMODEL, N = DMODEL;
    extern __shared__ char smem[];                  // 24576 B dynamic
    uint16_t* As = (uint16_t*)smem;                 // [64][64]  8 KB
    uint16_t* Bs = (uint16_t*)(smem + 8192);        // [128][64] 16 KB
    const int tid  = threadIdx.x;
    const int wave = tid >> 6;
    const int lane = tid & 63;
    const int m0 = blockIdx.y * 64;
    const int n0 = blockIdx.x * 128;
    const int lr   = lane & 15;
    const int quad = lane >> 4;

    floatx4 acc[4][2];
#pragma unroll
    for (int i = 0; i < 4; ++i)
#pragma unroll
        for (int j = 0; j < 2; ++j) acc[i][j] = (floatx4)0.0f;

    for (int k0 = 0; k0 < K; k0 += 64) {
#pragma unroll
        for (int i = 0; i < 2; ++i) {               // A: 512 chunks (16B)
            int c = i * 256 + tid;
            int r = c >> 3, s = (c & 7) ^ (r & 7);
            const uint16_t* g = A + (size_t)(m0 + r) * K + k0 + s * 8;
            __builtin_amdgcn_global_load_lds((const __attribute__((address_space(1))) void*)g,
                                             (__attribute__((address_space(3))) void*)(As + (size_t)c * 8), 16, 0, 0);
        }
#pragma unroll
        for (int i = 0; i < 4; ++i) {               // B: 1024 chunks
            int c = i * 256 + tid;
            int r = c >> 3, s = (c & 7) ^ (r & 7);
            const uint16_t* g = Bt + (size_t)(n0 + r) * K + k0 + s * 8;
            __builtin_amdgcn_global_load_lds((const __attribute__((address_space(1))) void*)g,
                                             (__attribute__((address_space(3))) void*)(Bs + (size_t)c * 8), 16, 0, 0);
        }
        __syncthreads();
#pragma unroll
        for (int ks = 0; ks < 2; ++ks) {            // two 32-wide k-halves
            bf16x8 af[4], bfr[2];
#pragma unroll
            for (int mi = 0; mi < 4; ++mi) {
                int row = mi * 16 + lr;
                af[mi] = *(const bf16x8*)&As[row * 64 + (((ks * 4 + quad) ^ (row & 7)) << 3)];
            }
#pragma unroll
            for (int ni = 0; ni < 2; ++ni) {
                int row = wave * 32 + ni * 16 + lr;
                bfr[ni] = *(const bf16x8*)&Bs[row * 64 + (((ks * 4 + quad) ^ (row & 7)) << 3)];
            }
#pragma unroll
            for (int mi = 0; mi < 4; ++mi)
#pragma unroll
                for (int ni = 0; ni < 2; ++ni)
                    acc[mi][ni] = __builtin_amdgcn_mfma_f32_16x16x32_bf16(af[mi], bfr[ni], acc[mi][ni], 0, 0, 0);
        }
        __syncthreads();
    }
    if constexpr (MODE == 1) {
        uint16_t* Ct = (uint16_t*)smem;             // [128][72], 18.4 KB
        const int bb = m0 >> 11, t0 = m0 & 2047;
#pragma unroll
        for (int mi = 0; mi < 4; ++mi)
#pragma unroll
            for (int ni = 0; ni < 2; ++ni) {
                int cl = wave * 32 + ni * 16 + lr;
                int tl = mi * 16 + quad * 4;
                int tls = tl ^ ((cl & 3) << 4);     // 2-way-only bank pattern
                union { uint16_t u[4]; uint64_t v8; } pk;
#pragma unroll
                for (int r = 0; r < 4; ++r) pk.u[r] = f2bf(acc[mi][ni][r]);
                *(uint64_t*)&Ct[cl * 72 + tls] = pk.v8;
            }
        __syncthreads();
#pragma unroll
        for (int k = 0; k < 4; ++k) {
            int c = k * 256 + tid;                  // 1024 chunks of 16B
            int cl = c >> 3, off = (c & 7) * 8;
            int offs = off ^ ((cl & 3) << 4);
            uint4 v = *(const uint4*)&Ct[cl * 72 + offs];
            *(uint4*)&outB[((size_t)(bb * 1024 + n0 + cl)) * 2048 + t0 + off] = v;
        }
    } else {
#pragma unroll
        for (int mi = 0; mi < 4; ++mi)
#pragma unroll
            for (int ni = 0; ni < 2; ++ni) {
                int col = n0 + wave * 32 + ni * 16 + lr;
#pragma unroll
                for (int r = 0; r < 4; ++r) {
                    int row = m0 + mi * 16 + quad * 4 + r;
                    outB[(size_t)row * N + col] = f2bf(acc[mi][ni][r]);
                }
            }
    }
}

__global__ __launch_bounds__(256) void mha_gemm_qkv(
    const uint16_t* __restrict__ A,
    const uint16_t* __restrict__ Wq, const uint16_t* __restrict__ Wk, const uint16_t* __restrict__ Wv,
    uint16_t* __restrict__ Q, uint16_t* __restrict__ K, uint16_t* __restrict__ Vt) {
    switch (blockIdx.z) {
        case 0:  gemm_bk64_body<0>(A, Wq, Q);  break;
        case 1:  gemm_bk64_body<0>(A, Wk, K);  break;
        default: gemm_bk64_body<1>(A, Wv, Vt); break;
    }
}

// ---- out-projection GEMM: 64M x 128N, BK=64, 512 thr / 8 waves ----
// (R14-best config: wave-tile 32x32, grid (8,64) = 2 blocks/CU x 8 waves
// = 16 waves/CU. R15's 64x64 retile regressed ~3.6 µs — reverted.)
__global__ __launch_bounds__(512) void mha_gemm_out(
    const uint16_t* __restrict__ A, const uint16_t* __restrict__ Wot,
    float* __restrict__ out, const float* __restrict__ bias) {
    const int K = DMODEL, N = DMODEL;
    extern __shared__ char smem[];                  // 24576 B dynamic
    uint16_t* As = (uint16_t*)smem;                 // [64][64]  8 KB
    uint16_t* Bs = (uint16_t*)(smem + 8192);        // [128][64] 16 KB
    const int tid  = threadIdx.x;
    const int wave = tid >> 6;
    const int lane = tid & 63;
    const int m0 = blockIdx.y * 64;
    const int n0 = blockIdx.x * 128;
    const int lr   = lane & 15;
    const int quad = lane >> 4;
    const int wm = wave >> 2, wn = wave & 3;        // 2m x 4n wave grid

    floatx4 acc[2][2];
#pragma unroll
    for (int i = 0; i < 2; ++i)
#pragma unroll
        for (int j = 0; j < 2; ++j) acc[i][j] = (floatx4)0.0f;

    for (int k0 = 0; k0 < K; k0 += 64) {
        {                                           // A: 512 chunks
            int c = tid;
            int r = c >> 3, s = (c & 7) ^ (r & 7);
            const uint16_t* g = A + (size_t)(m0 + r) * K + k0 + s * 8;
            __builtin_amdgcn_global_load_lds((const __attribute__((address_space(1))) void*)g,
                                             (__attribute__((address_space(3))) void*)(As + (size_t)c * 8), 16, 0, 0);
        }
#pragma unroll
        for (int i = 0; i < 2; ++i) {               // B: 1024 chunks
            int c = i * 512 + tid;
            int r = c >> 3, s = (c & 7) ^ (r & 7);
            const uint16_t* g = Wot + (size_t)(n0 + r) * K + k0 + s * 8;
            __builtin_amdgcn_global_load_lds((const __attribute__((address_space(1))) void*)g,
                                             (__attribute__((address_space(3))) void*)(Bs + (size_t)c * 8), 16, 0, 0);
        }
        __syncthreads();
#pragma unroll
        for (int ks = 0; ks < 2; ++ks) {
            bf16x8 af[2], bfr[2];
#pragma unroll
            for (int mi = 0; mi < 2; ++mi) {
                int row = wm * 32 + mi * 16 + lr;
                af[mi] = *(const bf16x8*)&As[row * 64 + (((ks * 4 + quad) ^ (row & 7)) << 3)];
            }
#pragma unroll
            for (int ni = 0; ni < 2; ++ni) {
                int row = wn * 32 + ni * 16 + lr;
                bfr[ni] = *(const bf16x8*)&Bs[row * 64 + (((ks * 4 + quad) ^ (row & 7)) << 3)];
            }
#pragma unroll
            for (int mi = 0; mi < 2; ++mi)
#pragma unroll
                for (int ni = 0; ni < 2; ++ni)
                    acc[mi][ni] = __builtin_amdgcn_mfma_f32_16x16x32_bf16(af[mi], bfr[ni], acc[mi][ni], 0, 0, 0);
        }
        __syncthreads();
    }
#pragma unroll
    for (int mi = 0; mi < 2; ++mi)
#pragma unroll
        for (int ni = 0; ni < 2; ++ni) {
            int col = n0 + wn * 32 + ni * 16 + lr;
            float bv = bias[col];
#pragma unroll
            for (int r = 0; r < 4; ++r) {
                int row = m0 + wm * 32 + mi * 16 + quad * 4 + r;
                out[(size_t)row * N + col] = acc[mi][ni][r] + bv;
            }
        }
}

// ---------------- MFMA flash attention (causal, fixed-base softmax) -------
// R10: the drain bug. Every __syncthreads() emits s_waitcnt vmcnt(0) —
// it drains the prefetch issued THIS iteration, so R2-R9's "double
// buffering" never overlapped anything: each iter paid full load latency
// serially (~5-6 B/cyc/CU per block; ~10 with 2 blocks/CU as the other
// block's compute covers the drain; qkv at 6 blocks/CU gets ~23). R0 had
// the fix (counted vmcnt + raw s_barrier, m139 pattern) but its heavy
// P-LDS softmax hid the benefit; the R2 rewrite dropped it. This round:
// light chain + q-tile 128 (half staged bytes) + R0's sync skeleton.
//   * 512 thr (__launch_bounds__(512,2): spill-free 92 VGPR, R7), 8
//     waves = 4 qg(32 q-rows) x 2 kvh(64 kv). q-tile 128, pairs jH=15-p,
//     jL=p (p=0..7); kv supertile 128; TH=16-p, TH+TL=17 iters. Grid
//     (16,8,2) = 256 = 1 block/CU. Staged 544 KB/CU.
//   * 3-buffer rotation, depth-2 prefetch: stage(t+2) at top; at bottom
//     s_waitcnt vmcnt(4) (this iter's 4 staged loads may fly; last
//     iter's 4 — tile t+1 — must have landed) + raw s_barrier. t+1's
//     loads get a FULL iteration of compute to cover their latency.
//   * combine_store (2-way kvh merge) keeps plain __syncthreads(); its
//     vmcnt(0) drain fires only twice per block. o-scratch = dead
//     Ks[cur] (qg 0-1) / Vs[cur] (qg 2-3), 16 KB each.
// In-reg softmax (swapped QK^T -> exp2 -> cvt_pk -> permlane32_swap) and
// all swizzles carried verbatim from the R2/R6-verified code.
__global__ __launch_bounds__(512, 2) void mha_attn_mfma(
    const uint16_t* __restrict__ Q, const uint16_t* __restrict__ K,
    const uint16_t* __restrict__ Vt, uint16_t* __restrict__ ctx) {
    extern __shared__ char asmem[];
    uint16_t* Ks0 = (uint16_t*)asmem;              // [3][128*64] 48 KB [kv][d]
    uint16_t* Vs0 = (uint16_t*)(asmem + 49152);    // [3][64*128] 48 KB [d][kv]
    float*    lbuf = (float*)(asmem + 98304);      // 256 f32 l/linv scratch

    const int tid  = threadIdx.x;
    const int wave = tid >> 6;
    const int lane = tid & 63;
    const int l31  = lane & 31;
    const int hi   = lane >> 5;
    const int l7   = lane & 7;
    const int qg   = wave & 3;             // q-row group (32 rows, 4 groups)
    const int kvh  = wave >> 2;            // kv half: [0,64) / [64,128)
    const int h = blockIdx.x;              // head fastest -> XCD locality
    const int p = blockIdx.y;              // 0..7
    const int b = blockIdx.z;
    const int jH = 15 - p, jL = p;         // paired 128-row q-tiles
    const int TH = jH + 1;                 // 128-wide supertiles; TH+TL=17

    // staging: 2 K chunks + 2 V chunks per thread, XOR source swizzle,
    // linear LDS dest (R6-verified pattern)
    const uint16_t* kg[2];
    const uint16_t* vg[2];
    int cch[2];
#pragma unroll
    for (int i = 0; i < 2; ++i) {
        int c = i * 512 + tid; cch[i] = c;        // chunk 0..1023 (16 B)
        int rk = c >> 3, ck = c & 7;              // K: 128 rows x 8 chunks
        kg[i] = K + ((size_t)(b * SEQ_T) + rk) * DMODEL + h * DHEAD + ((ck ^ (rk & 7)) * 8);
        int rv = c >> 4, cv = c & 15;             // V: 64 rows x 16 chunks
        int sv = (cv & 8) | ((cv & 7) ^ (rv & 7));
        vg[i] = Vt + ((size_t)(b * 1024 + h * DHEAD + rv)) * 2048 + sv * 8;
    }

    int q0w = jH * 128 + qg * 32;          // this wave's q base
    bf16x8 qf[4];
    auto load_q = [&]() {
        const uint16_t* qb = Q + ((size_t)(b * SEQ_T) + q0w + l31) * DMODEL + h * DHEAD;
#pragma unroll
        for (int f = 0; f < 4; ++f)
            qf[f] = *(const bf16x8*)(qb + f * 16 + hi * 8);
    };
    load_q();

    floatx16 o[2];
#pragma unroll
    for (int dt = 0; dt < 2; ++dt) o[dt] = (floatx16)0.0f;
    float lac = 0.f;

    auto stage = [&](int kv0, int buf) {   // exactly 4 global_load_lds/thread
        uint16_t* kd = Ks0 + buf * 8192;
        uint16_t* vd = Vs0 + buf * 8192;
#pragma unroll
        for (int i = 0; i < 2; ++i) {
            __builtin_amdgcn_global_load_lds(
                (const __attribute__((address_space(1))) void*)(kg[i] + (size_t)kv0 * DMODEL),
                (__attribute__((address_space(3))) void*)(kd + cch[i] * 8), 16, 0, 0);
            __builtin_amdgcn_global_load_lds(
                (const __attribute__((address_space(1))) void*)(vg[i] + kv0),
                (__attribute__((address_space(3))) void*)(vd + cch[i] * 8), 16, 0, 0);
        }
    };
    auto kvof = [&](int t) { return (t < TH ? t : t - TH) * 128; };

    // own + partner-half value (lane l <-> l^32) summed
    auto halfsum = [&](float x) -> float {
#if __has_builtin(__builtin_amdgcn_permlane32_swap)
        uint32x2 r = __builtin_amdgcn_permlane32_swap(__float_as_uint(x), __float_as_uint(x), false, false);
        return __uint_as_float(r.x) + __uint_as_float(r.y);
#else
        return x + __shfl_xor(x, 32, 64);
#endif
    };

    // merge kvh=1 partials into kvh=0 (fixed-base softmax => o,l additive).
    // o-scratch = dead buffers of slot cur: Ks[cur] (qg 0-1), Vs[cur]
    // (qg 2-3), each [64 q][64 d] f32 = 16 KB. In-flight DMA targets
    // (t+1)%3 and (t+2)%3, both != cur; the __syncthreads drains them
    // early (harmless, twice per block).
    auto combine_store = [&](int cur) {
        __syncthreads();
        float* osc = (qg < 2) ? (float*)(Ks0 + cur * 8192)
                              : (float*)(Vs0 + cur * 8192);
        const int qoff = (qg & 1) * 32;
        float lt = halfsum(lac);
        if (kvh == 1) {
#pragma unroll
            for (int dt = 0; dt < 2; ++dt)
#pragma unroll
                for (int r = 0; r < 16; ++r) {
                    int row = (r & 3) + 8 * (r >> 2) + 4 * hi;
                    osc[(qoff + row) * 64 + dt * 32 + l31] = o[dt][r];
                }
            if (lane < 32) lbuf[qg * 32 + lane] = lt;
        }
        __syncthreads();
        if (kvh == 0) {
            float ltot = lt + lbuf[qg * 32 + l31];
            if (lane < 32) lbuf[128 + qg * 32 + lane] = 1.f / ltot;
#pragma unroll
            for (int dt = 0; dt < 2; ++dt)
#pragma unroll
                for (int r = 0; r < 16; ++r) {
                    int row = (r & 3) + 8 * (r >> 2) + 4 * hi;
                    float ov = o[dt][r] + osc[(qoff + row) * 64 + dt * 32 + l31];
                    float li = lbuf[128 + qg * 32 + row];   // same-wave read
                    size_t addr = ((size_t)(b * SEQ_T) + q0w + row) * DMODEL + h * DHEAD + dt * 32 + l31;
                    ctx[addr] = f2bf(ov * li);
                }
        }
    };

    stage(kvof(0), 0);
    stage(kvof(1), 1);                     // 8 loads in flight
    // wait oldest 4 (tile 0) only; tile 1 keeps flying across the barrier
    __builtin_amdgcn_s_waitcnt(0x0F74);    // vmcnt(4), lgkm/exp no-wait
    __builtin_amdgcn_s_barrier();

    for (int t = 0; t < 17; ++t) {
        const int cur = t % 3;
        const int kv0 = kvof(t);
        if (t + 2 < 17) stage(kvof(t + 2), (t + 2) % 3);
        const uint16_t* Kc = Ks0 + cur * 8192;
        const uint16_t* Vc = Vs0 + cur * 8192;
#pragma unroll
        for (int kt = 0; kt < 2; ++kt) {
            const int kb = kv0 + kvh * 64 + kt * 32;
            // QK^T swapped: S^T[k][q] = mfma(K, Q); lane: q = l31, k by reg
            floatx16 s = (floatx16)0.0f;
            __builtin_amdgcn_s_setprio(1);
#pragma unroll
            for (int f = 0; f < 4; ++f) {
                bf16x8 kf = *(const bf16x8*)&Kc[(kvh * 64 + kt * 32 + l31) * 64 + (((2 * f + hi) ^ l7) << 3)];
                s = __builtin_amdgcn_mfma_f32_32x32x16_bf16(kf, qf[f], s, 0, 0, 0);
            }
            __builtin_amdgcn_s_setprio(0);
            if (kb + 31 > q0w) {           // causal mask (covers overhang)
                int qr = q0w + l31;
#pragma unroll
                for (int r = 0; r < 16; ++r) {
                    int k = kb + (r & 3) + 8 * (r >> 2) + 4 * hi;
                    if (k > qr) s[r] = -3e38f;
                }
            }
            // p = exp2(s) (scale folded into W_q); l rides a VALU sum.
            uint32_t d0[2], d1[2], d2[2], d3[2];
#pragma unroll
            for (int i = 0; i < 2; ++i) {
                float a, c2;
                a = __builtin_amdgcn_exp2f(s[2 * i]);      c2 = __builtin_amdgcn_exp2f(s[2 * i + 1]);
                lac += a + c2; d0[i] = pack2bf(a, c2);
                a = __builtin_amdgcn_exp2f(s[4 + 2 * i]);  c2 = __builtin_amdgcn_exp2f(s[4 + 2 * i + 1]);
                lac += a + c2; d1[i] = pack2bf(a, c2);
                a = __builtin_amdgcn_exp2f(s[8 + 2 * i]);  c2 = __builtin_amdgcn_exp2f(s[8 + 2 * i + 1]);
                lac += a + c2; d2[i] = pack2bf(a, c2);
                a = __builtin_amdgcn_exp2f(s[12 + 2 * i]); c2 = __builtin_amdgcn_exp2f(s[12 + 2 * i + 1]);
                lac += a + c2; d3[i] = pack2bf(a, c2);
            }
            // redistribute across lane halves -> PV A-frags (k contiguous)
            bf16x8 paf[2];
#if __has_builtin(__builtin_amdgcn_permlane32_swap)
            {
                uint32x2 r0 = __builtin_amdgcn_permlane32_swap(d0[0], d1[0], false, false);
                uint32x2 r1 = __builtin_amdgcn_permlane32_swap(d0[1], d1[1], false, false);
                union { uint32_t u[4]; bf16x8 v; } f0;
                f0.u[0] = r0.x; f0.u[1] = r1.x; f0.u[2] = r0.y; f0.u[3] = r1.y;
                paf[0] = f0.v;
                uint32x2 r2 = __builtin_amdgcn_permlane32_swap(d2[0], d3[0], false, false);
                uint32x2 r3 = __builtin_amdgcn_permlane32_swap(d2[1], d3[1], false, false);
                union { uint32_t u[4]; bf16x8 v; } f1;
                f1.u[0] = r2.x; f1.u[1] = r3.x; f1.u[2] = r2.y; f1.u[3] = r3.y;
                paf[1] = f1.v;
            }
#else
            {
                uint32_t s00 = __shfl_xor((int)d0[0], 32, 64), s01 = __shfl_xor((int)d0[1], 32, 64);
                uint32_t s10 = __shfl_xor((int)d1[0], 32, 64), s11 = __shfl_xor((int)d1[1], 32, 64);
                union { uint32_t u[4]; bf16x8 v; } f0;
                f0.u[0] = hi ? s10 : d0[0]; f0.u[1] = hi ? s11 : d0[1];
                f0.u[2] = hi ? d1[0] : s00; f0.u[3] = hi ? d1[1] : s01;
                paf[0] = f0.v;
                uint32_t s20 = __shfl_xor((int)d2[0], 32, 64), s21 = __shfl_xor((int)d2[1], 32, 64);
                uint32_t s30 = __shfl_xor((int)d3[0], 32, 64), s31 = __shfl_xor((int)d3[1], 32, 64);
                union { uint32_t u[4]; bf16x8 v; } f1;
                f1.u[0] = hi ? s30 : d2[0]; f1.u[1] = hi ? s31 : d2[1];
                f1.u[2] = hi ? d3[0] : s20; f1.u[3] = hi ? d3[1] : s21;
                paf[1] = f1.v;
            }
#endif
            // PV: O[q][d] += P x V  (A = in-reg P, B = V^T rows from LDS)
            __builtin_amdgcn_s_setprio(1);
#pragma unroll
            for (int f = 0; f < 2; ++f)
#pragma unroll
                for (int dt = 0; dt < 2; ++dt) {
                    bf16x8 vf = *(const bf16x8*)&Vc[(dt * 32 + l31) * 128 + ((kvh * 8 + ((kt * 4 + 2 * f + hi) ^ l7)) << 3)];
                    o[dt] = __builtin_amdgcn_mfma_f32_32x32x16_bf16(paf[f], vf, o[dt], 0, 0, 0);
                }
            __builtin_amdgcn_s_setprio(0);
        }
        if (t == TH - 1) {                 // high q-tile done: merge + store
            combine_store(cur);
            q0w = jL * 128 + qg * 32;
            load_q();
#pragma unroll
            for (int dt = 0; dt < 2; ++dt) o[dt] = (floatx16)0.0f;
            lac = 0.f;
        }
        // end-of-iter sync: drain only the oldest outstanding stage (tile
        // t+1, issued a full iteration ago); the stage issued THIS iter
        // (t+2) crosses the barrier still in flight. Last tile: no barrier.
        if (t + 2 < 17) {
            __builtin_amdgcn_s_waitcnt(0x0F74);    // vmcnt(4)
            __builtin_amdgcn_s_barrier();
        } else if (t + 1 < 17) {
            __builtin_amdgcn_s_waitcnt(0x0F70);    // vmcnt(0): final drain
            __builtin_amdgcn_s_barrier();
        }
    }
    combine_store(16 % 3);                 // t=16 -> cur=1
}

extern "C" void kernel_launch(void* const* d_in, const int* in_sizes, int n_in,
                              void* d_out, int out_size, void* d_ws, size_t ws_size,
                              hipStream_t stream) {
    const float* x  = (const float*)d_in[0];
    const float* Wq = (const float*)d_in[1];
    const float* Wk = (const float*)d_in[2];
    const float* Wv = (const float*)d_in[3];
    const float* Wo = (const float*)d_in[4];
    const float* bo = (const float*)d_in[5];
    float* out = (float*)d_out;

    char* ws = (char*)d_ws;
    const size_t SZ_X = (size_t)4096 * DMODEL * 2;   // 8 MB
    const size_t SZ_W = (size_t)DMODEL * DMODEL * 2; // 2 MB
    size_t off = 0;
    uint16_t* xb  = (uint16_t*)(ws + off); off += SZ_X;
    uint16_t* wqt = (uint16_t*)(ws + off); off += SZ_W;
    uint16_t* wkt = (uint16_t*)(ws + off); off += SZ_W;
    uint16_t* wvt = (uint16_t*)(ws + off); off += SZ_W;
    uint16_t* wot = (uint16_t*)(ws + off); off += SZ_W;
    uint16_t* Qb  = (uint16_t*)(ws + off); off += SZ_X;
    uint16_t* Kb  = (uint16_t*)(ws + off); off += SZ_X;
    uint16_t* Vtb = (uint16_t*)(ws + off); off += SZ_X;  // per-head transposed V
    uint16_t* Cb  = (uint16_t*)(ws + off); off += SZ_X;
    (void)ws_size; (void)in_sizes; (void)n_in; (void)out_size;

    mha_cvt<<<dim3(16, 16, 5), 256, 0, stream>>>(x, xb, Wq, Wk, Wv, Wo, wqt, wkt, wvt, wot);
    mha_gemm_qkv<<<dim3(8, 64, 3), 256, 24576, stream>>>(xb, wqt, wkt, wvt, Qb, Kb, Vtb);
    mha_attn_mfma<<<dim3(NHEAD, 8, 2), 512, 99328, stream>>>(Qb, Kb, Vtb, Cb);
    mha_gemm_out<<<dim3(8, 64), 512, 24576, stream>>>(Cb, wot, out, bo);
}